// Round 1
// baseline (491.090 us; speedup 1.0000x reference)
//
#include <hip/hip_runtime.h>
#include <hip/hip_bf16.h>

// Sizes fixed by the problem
#define BB 8
#define TT 2048
#define CC 512     // IN_FEAT
#define DD 512     // D_FEAT
#define HH 8
#define DH 64

typedef __bf16 bf16x8 __attribute__((ext_vector_type(8)));
typedef float  f32x4  __attribute__((ext_vector_type(4)));

// ---------------------------------------------------------------------------
// Kernel 1: LayerNorm over channel dim + transpose (B,C,T) fp32 -> (B*T, C) bf16
// block: 256 threads handles 32 t positions x all 512 channels
// ---------------------------------------------------------------------------
__global__ __launch_bounds__(256) void ln_kernel(
    const float* __restrict__ x, const float* __restrict__ gamma,
    const float* __restrict__ beta, __hip_bfloat16* __restrict__ h)
{
    const int b  = blockIdx.x >> 6;          // T/32 = 64 tiles per batch
    const int t0 = (blockIdx.x & 63) * 32;
    const int tid = threadIdx.x;
    const int tl = tid & 31;                 // t within tile
    const int part = tid >> 5;               // 0..7 channel partition

    const float* xb = x + (size_t)b * CC * TT;

    float sum = 0.f, sq = 0.f;
    for (int ci = 0; ci < 64; ++ci) {
        int c = part * 64 + ci;
        float v = xb[(size_t)c * TT + t0 + tl];
        sum += v; sq += v * v;
    }
    __shared__ float sA[8][32], sB[8][32];
    sA[part][tl] = sum; sB[part][tl] = sq;
    __syncthreads();
    __shared__ float s_mu[32], s_rstd[32];
    if (part == 0) {
        float s = 0.f, q = 0.f;
        for (int p = 0; p < 8; ++p) { s += sA[p][tl]; q += sB[p][tl]; }
        float mu  = s * (1.0f / 512.0f);
        float var = q * (1.0f / 512.0f) - mu * mu;
        s_mu[tl] = mu;
        s_rstd[tl] = rsqrtf(var + 1e-5f);
    }
    __syncthreads();

    const float mu = s_mu[tl], rstd = s_rstd[tl];
    __shared__ __hip_bfloat16 tileT[32][72];   // 32 t x 64 c chunk (pad 8)

    for (int chunk = 0; chunk < 8; ++chunk) {
        int cb = chunk * 64 + part * 8;
        #pragma unroll
        for (int j = 0; j < 8; ++j) {
            int c = cb + j;
            float v = xb[(size_t)c * TT + t0 + tl];
            float nv = (v - mu) * rstd * gamma[c] + beta[c];
            tileT[tl][part * 8 + j] = __float2bfloat16(nv);
        }
        __syncthreads();
        int cl = tid & 63, tw = tid >> 6;
        #pragma unroll
        for (int k = 0; k < 8; ++k) {
            int t = tw + k * 4;
            h[((size_t)(b * TT + t0 + t)) * CC + chunk * 64 + cl] = tileT[t][cl];
        }
        __syncthreads();
    }
}

// ---------------------------------------------------------------------------
// Kernel 2: weight prepack: w (K=512, N=512) fp32 row-major -> wt (N, K) bf16
// ---------------------------------------------------------------------------
__global__ __launch_bounds__(256) void prepack_w(
    const float* __restrict__ w, __hip_bfloat16* __restrict__ wt)
{
    __shared__ float tile[32][33];
    const int bx = blockIdx.x & 15;   // n tile
    const int by = blockIdx.x >> 4;   // k tile
    const int lx = threadIdx.x & 31, ly = threadIdx.x >> 5;
    #pragma unroll
    for (int i = 0; i < 4; ++i) {
        int k = by * 32 + ly + i * 8;
        tile[ly + i * 8][lx] = w[(size_t)k * 512 + bx * 32 + lx];
    }
    __syncthreads();
    #pragma unroll
    for (int i = 0; i < 4; ++i) {
        int n = bx * 32 + ly + i * 8;
        wt[(size_t)n * 512 + by * 32 + lx] = __float2bfloat16(tile[lx][ly + i * 8]);
    }
}

// ---------------------------------------------------------------------------
// Kernel 3: fused QKV GEMM.  A = h (16384 x 512) bf16 row-major.
// WT* = (N,K) bf16. Out: q/k/v in (B,H,T,dh) bf16.  blockIdx.z picks matrix.
// 128x128 tile, 4 waves (2x2), each wave 64x64 = 4x4 16x16 MFMA tiles.
// ---------------------------------------------------------------------------
__global__ __launch_bounds__(256) void qkv_gemm(
    const __hip_bfloat16* __restrict__ A,
    const __hip_bfloat16* __restrict__ wtq, const __hip_bfloat16* __restrict__ wtk,
    const __hip_bfloat16* __restrict__ wtv,
    const float* __restrict__ bq, const float* __restrict__ bk,
    const float* __restrict__ bv,
    __hip_bfloat16* __restrict__ qo, __hip_bfloat16* __restrict__ ko,
    __hip_bfloat16* __restrict__ vo)
{
    const int m0 = blockIdx.x * 128;
    const int n0 = blockIdx.y * 128;
    const __hip_bfloat16* WT; const float* bias; __hip_bfloat16* out;
    if (blockIdx.z == 0)      { WT = wtq; bias = bq; out = qo; }
    else if (blockIdx.z == 1) { WT = wtk; bias = bk; out = ko; }
    else                      { WT = wtv; bias = bv; out = vo; }

    __shared__ __hip_bfloat16 As[128][40];
    __shared__ __hip_bfloat16 Bs[128][40];

    const int tid = threadIdx.x;
    const int wave = tid >> 6, lane = tid & 63;
    const int quad = lane >> 4, l16 = lane & 15;
    const int wy = wave >> 1, wx = wave & 1;

    f32x4 acc[4][4] = {};

    for (int kt = 0; kt < 512; kt += 32) {
        #pragma unroll
        for (int i = 0; i < 2; ++i) {
            int row = (tid >> 2) + i * 64;
            int kofs = (tid & 3) * 8;
            *reinterpret_cast<bf16x8*>(&As[row][kofs]) =
                *reinterpret_cast<const bf16x8*>(&A[(size_t)(m0 + row) * 512 + kt + kofs]);
            *reinterpret_cast<bf16x8*>(&Bs[row][kofs]) =
                *reinterpret_cast<const bf16x8*>(&WT[(size_t)(n0 + row) * 512 + kt + kofs]);
        }
        __syncthreads();
        bf16x8 af[4], bfr[4];
        #pragma unroll
        for (int mt = 0; mt < 4; ++mt)
            af[mt] = *reinterpret_cast<const bf16x8*>(&As[wy * 64 + mt * 16 + l16][quad * 8]);
        #pragma unroll
        for (int nt = 0; nt < 4; ++nt)
            bfr[nt] = *reinterpret_cast<const bf16x8*>(&Bs[wx * 64 + nt * 16 + l16][quad * 8]);
        #pragma unroll
        for (int mt = 0; mt < 4; ++mt)
            #pragma unroll
            for (int nt = 0; nt < 4; ++nt)
                acc[mt][nt] = __builtin_amdgcn_mfma_f32_16x16x32_bf16(
                    af[mt], bfr[nt], acc[mt][nt], 0, 0, 0);
        __syncthreads();
    }

    // epilogue: C row = quad*4+r (m, i.e. t), col = l16 (n, i.e. d)
    #pragma unroll
    for (int nt = 0; nt < 4; ++nt) {
        int n = n0 + wx * 64 + nt * 16 + l16;
        int hh = n >> 6, di = n & 63;
        float bval = bias[n];
        #pragma unroll
        for (int mt = 0; mt < 4; ++mt) {
            #pragma unroll
            for (int r = 0; r < 4; ++r) {
                int m = m0 + wy * 64 + mt * 16 + quad * 4 + r;
                int b = m >> 11, t = m & 2047;
                out[((size_t)((b * HH + hh) * TT + t)) * DH + di] =
                    __float2bfloat16(acc[mt][nt][r] + bval);
            }
        }
    }
}

// ---------------------------------------------------------------------------
// Kernel 4: causal flash attention.  Q/K/V: (B,H,T,64) bf16 -> ctx (B*T, 512) bf16
// block = 256 thr (4 waves); block handles (bh, 64 q rows); wave = 16 q rows.
// ---------------------------------------------------------------------------
__global__ __launch_bounds__(256) void attn_kernel(
    const __hip_bfloat16* __restrict__ Q, const __hip_bfloat16* __restrict__ K,
    const __hip_bfloat16* __restrict__ V, __hip_bfloat16* __restrict__ ctx)
{
    const int q0 = blockIdx.x * 64;
    const int bh = blockIdx.y;
    const __hip_bfloat16* Qb = Q + (size_t)bh * TT * DH;
    const __hip_bfloat16* Kb = K + (size_t)bh * TT * DH;
    const __hip_bfloat16* Vb = V + (size_t)bh * TT * DH;

    const int tid = threadIdx.x, wave = tid >> 6, lane = tid & 63;
    const int quad = lane >> 4, l16 = lane & 15;

    __shared__ __hip_bfloat16 Ks[64][72];
    __shared__ __hip_bfloat16 Vs[64][72];
    __shared__ __hip_bfloat16 Ps[4][16][72];

    // Q fragments (A layout: m = l16, k = st*32 + quad*8 + j)
    bf16x8 qf[2];
    const int qrow = q0 + wave * 16 + l16;
    #pragma unroll
    for (int s = 0; s < 2; ++s)
        qf[s] = *reinterpret_cast<const bf16x8*>(&Qb[(size_t)qrow * DH + s * 32 + quad * 8]);

    f32x4 o_acc[4] = {};
    float m_run[4], l_run[4];
    #pragma unroll
    for (int r = 0; r < 4; ++r) { m_run[r] = -1e30f; l_run[r] = 0.f; }

    const int kend = q0 + 64;
    for (int k0 = 0; k0 < kend; k0 += 64) {
        // stage K, V tiles
        {
            int rr = tid >> 3;
            int co = (tid & 7) * 8;
            #pragma unroll
            for (int i = 0; i < 2; ++i) {
                int r2 = rr + i * 32;
                *reinterpret_cast<bf16x8*>(&Ks[r2][co]) =
                    *reinterpret_cast<const bf16x8*>(&Kb[(size_t)(k0 + r2) * DH + co]);
                *reinterpret_cast<bf16x8*>(&Vs[r2][co]) =
                    *reinterpret_cast<const bf16x8*>(&Vb[(size_t)(k0 + r2) * DH + co]);
            }
        }
        __syncthreads();

        // S = Q K^T  (4 n-tiles of 16)
        f32x4 s[4];
        #pragma unroll
        for (int nt = 0; nt < 4; ++nt) {
            f32x4 z = {};
            #pragma unroll
            for (int st = 0; st < 2; ++st) {
                bf16x8 kf = *reinterpret_cast<const bf16x8*>(
                    &Ks[nt * 16 + l16][st * 32 + quad * 8]);
                z = __builtin_amdgcn_mfma_f32_16x16x32_bf16(qf[st], kf, z, 0, 0, 0);
            }
            s[nt] = z;
        }

        // scale + causal mask; row = quad*4 + r, col = k0 + nt*16 + l16
        const int qbase = q0 + wave * 16 + quad * 4;
        float mtile[4] = {-1e30f, -1e30f, -1e30f, -1e30f};
        #pragma unroll
        for (int nt = 0; nt < 4; ++nt) {
            int kg = k0 + nt * 16 + l16;
            #pragma unroll
            for (int r = 0; r < 4; ++r) {
                float val = s[nt][r] * 0.125f;
                val = (kg > qbase + r) ? -1e9f : val;
                s[nt][r] = val;
                mtile[r] = fmaxf(mtile[r], val);
            }
        }
        // online softmax update
        #pragma unroll
        for (int r = 0; r < 4; ++r) {
            float mv = mtile[r];
            #pragma unroll
            for (int off = 1; off < 16; off <<= 1)
                mv = fmaxf(mv, __shfl_xor(mv, off, 64));
            float mnew = fmaxf(m_run[r], mv);
            float alpha = __expf(m_run[r] - mnew);
            m_run[r] = mnew;
            l_run[r] *= alpha;
            #pragma unroll
            for (int dt = 0; dt < 4; ++dt) o_acc[dt][r] *= alpha;
            mtile[r] = mnew;
        }
        // P = exp(s - m); write to LDS in A layout; accumulate row sums
        float rs[4] = {0.f, 0.f, 0.f, 0.f};
        #pragma unroll
        for (int nt = 0; nt < 4; ++nt) {
            #pragma unroll
            for (int r = 0; r < 4; ++r) {
                float p = __expf(s[nt][r] - mtile[r]);
                rs[r] += p;
                Ps[wave][quad * 4 + r][nt * 16 + l16] = __float2bfloat16(p);
            }
        }
        #pragma unroll
        for (int r = 0; r < 4; ++r) {
            float v = rs[r];
            #pragma unroll
            for (int off = 1; off < 16; off <<= 1)
                v += __shfl_xor(v, off, 64);
            l_run[r] += v;
        }

        // O += P V   (P: A layout from LDS; V: B layout scalar reads)
        bf16x8 pf[2];
        #pragma unroll
        for (int st = 0; st < 2; ++st)
            pf[st] = *reinterpret_cast<const bf16x8*>(&Ps[wave][l16][st * 32 + quad * 8]);
        #pragma unroll
        for (int dt = 0; dt < 4; ++dt) {
            #pragma unroll
            for (int st = 0; st < 2; ++st) {
                bf16x8 vf;
                #pragma unroll
                for (int j = 0; j < 8; ++j)
                    vf[j] = *reinterpret_cast<const __bf16*>(
                        &Vs[st * 32 + quad * 8 + j][dt * 16 + l16]);
                o_acc[dt] = __builtin_amdgcn_mfma_f32_16x16x32_bf16(
                    pf[st], vf, o_acc[dt], 0, 0, 0);
            }
        }
        __syncthreads();
    }

    // epilogue: ctx (B*T, 512); row t = qbase-ish, col = h*64 + dt*16 + l16
    const int b = bh >> 3, hh = bh & 7;
    #pragma unroll
    for (int r = 0; r < 4; ++r) {
        int t = q0 + wave * 16 + quad * 4 + r;
        float inv = 1.0f / l_run[r];
        #pragma unroll
        for (int dt = 0; dt < 4; ++dt) {
            ctx[((size_t)(b * TT + t)) * DD + hh * DH + dt * 16 + l16] =
                __float2bfloat16(o_acc[dt][r] * inv);
        }
    }
}

// ---------------------------------------------------------------------------
// Kernel 5: out-proj GEMM + bias + residual.  A = ctx (16384 x 512) bf16,
// WT = wo^T (N=512, K=512) bf16.  out(B,C,T) fp32 = x + A@wo + bo.
// ---------------------------------------------------------------------------
__global__ __launch_bounds__(256) void oproj_gemm(
    const __hip_bfloat16* __restrict__ A, const __hip_bfloat16* __restrict__ WT,
    const float* __restrict__ bo, const float* __restrict__ xres,
    float* __restrict__ outp)
{
    const int m0 = blockIdx.x * 128;
    const int n0 = blockIdx.y * 128;

    __shared__ __hip_bfloat16 As[128][40];
    __shared__ __hip_bfloat16 Bs[128][40];
    __shared__ float eps_t[4][16][17];

    const int tid = threadIdx.x;
    const int wave = tid >> 6, lane = tid & 63;
    const int quad = lane >> 4, l16 = lane & 15;
    const int wy = wave >> 1, wx = wave & 1;

    f32x4 acc[4][4] = {};

    for (int kt = 0; kt < 512; kt += 32) {
        #pragma unroll
        for (int i = 0; i < 2; ++i) {
            int row = (tid >> 2) + i * 64;
            int kofs = (tid & 3) * 8;
            *reinterpret_cast<bf16x8*>(&As[row][kofs]) =
                *reinterpret_cast<const bf16x8*>(&A[(size_t)(m0 + row) * 512 + kt + kofs]);
            *reinterpret_cast<bf16x8*>(&Bs[row][kofs]) =
                *reinterpret_cast<const bf16x8*>(&WT[(size_t)(n0 + row) * 512 + kt + kofs]);
        }
        __syncthreads();
        bf16x8 af[4], bfr[4];
        #pragma unroll
        for (int mt = 0; mt < 4; ++mt)
            af[mt] = *reinterpret_cast<const bf16x8*>(&As[wy * 64 + mt * 16 + l16][quad * 8]);
        #pragma unroll
        for (int nt = 0; nt < 4; ++nt)
            bfr[nt] = *reinterpret_cast<const bf16x8*>(&Bs[wx * 64 + nt * 16 + l16][quad * 8]);
        #pragma unroll
        for (int mt = 0; mt < 4; ++mt)
            #pragma unroll
            for (int nt = 0; nt < 4; ++nt)
                acc[mt][nt] = __builtin_amdgcn_mfma_f32_16x16x32_bf16(
                    af[mt], bfr[nt], acc[mt][nt], 0, 0, 0);
        __syncthreads();
    }

    // epilogue with per-wave LDS transpose: out[(b*512+n)*2048 + t]
    #pragma unroll
    for (int mt = 0; mt < 4; ++mt) {
        int mbase = m0 + wy * 64 + mt * 16;
        #pragma unroll
        for (int nt = 0; nt < 4; ++nt) {
            #pragma unroll
            for (int r = 0; r < 4; ++r)
                eps_t[wave][quad * 4 + r][l16] = acc[mt][nt][r];
            // wave-synchronous LDS exchange (single wave, compiler inserts lgkmcnt)
            #pragma unroll
            for (int pass = 0; pass < 4; ++pass) {
                int nl = pass * 4 + quad;
                int n = n0 + wx * 64 + nt * 16 + nl;
                int m = mbase + l16;
                int b = m >> 11, t = m & 2047;
                size_t oi = ((size_t)(b * CC + n)) * TT + t;
                outp[oi] = xres[oi] + eps_t[wave][l16][nl] + bo[n];
            }
        }
    }
}

// ---------------------------------------------------------------------------
extern "C" void kernel_launch(void* const* d_in, const int* in_sizes, int n_in,
                              void* d_out, int out_size, void* d_ws, size_t ws_size,
                              hipStream_t stream)
{
    const float* x     = (const float*)d_in[0];
    const float* gamma = (const float*)d_in[1];
    const float* beta  = (const float*)d_in[2];
    const float* wq    = (const float*)d_in[3];
    const float* bq    = (const float*)d_in[4];
    const float* wk    = (const float*)d_in[5];
    const float* bk    = (const float*)d_in[6];
    const float* wv    = (const float*)d_in[7];
    const float* bv    = (const float*)d_in[8];
    const float* wo    = (const float*)d_in[9];
    const float* bo    = (const float*)d_in[10];
    float* out = (float*)d_out;

    char* ws = (char*)d_ws;
    const size_t sz_big = (size_t)BB * TT * DD * sizeof(__hip_bfloat16); // 16 MB
    __hip_bfloat16* hbf = (__hip_bfloat16*)ws; ws += sz_big;
    __hip_bfloat16* qb  = (__hip_bfloat16*)ws; ws += sz_big;
    __hip_bfloat16* kb  = (__hip_bfloat16*)ws; ws += sz_big;
    __hip_bfloat16* vb  = (__hip_bfloat16*)ws; ws += sz_big;
    __hip_bfloat16* ctx = (__hip_bfloat16*)ws; ws += sz_big;
    const size_t sz_w = (size_t)512 * 512 * sizeof(__hip_bfloat16);
    __hip_bfloat16* wtq = (__hip_bfloat16*)ws; ws += sz_w;
    __hip_bfloat16* wtk = (__hip_bfloat16*)ws; ws += sz_w;
    __hip_bfloat16* wtv = (__hip_bfloat16*)ws; ws += sz_w;
    __hip_bfloat16* wto = (__hip_bfloat16*)ws; ws += sz_w;

    prepack_w<<<256, 256, 0, stream>>>(wq, wtq);
    prepack_w<<<256, 256, 0, stream>>>(wk, wtk);
    prepack_w<<<256, 256, 0, stream>>>(wv, wtv);
    prepack_w<<<256, 256, 0, stream>>>(wo, wto);

    ln_kernel<<<BB * (TT / 32), 256, 0, stream>>>(x, gamma, beta, hbf);

    qkv_gemm<<<dim3(BB * TT / 128, DD / 128, 3), 256, 0, stream>>>(
        hbf, wtq, wtk, wtv, bq, bk, bv, qb, kb, vb);

    attn_kernel<<<dim3(TT / 64, BB * HH), 256, 0, stream>>>(qb, kb, vb, ctx);

    oproj_gemm<<<dim3(BB * TT / 128, CC / 128), 256, 0, stream>>>(
        ctx, wto, bo, x, out);
}

// Round 2
// 374.684 us; speedup vs baseline: 1.3107x; 1.3107x over previous
//
#include <hip/hip_runtime.h>
#include <hip/hip_bf16.h>

#define BB 8
#define TT 2048
#define CC 512
#define DD 512
#define HH 8
#define DH 64

typedef __bf16 bf16x8 __attribute__((ext_vector_type(8)));
typedef __bf16 bf16x4 __attribute__((ext_vector_type(4)));
typedef float  f32x4  __attribute__((ext_vector_type(4)));

// ---------------------------------------------------------------------------
// Kernel 1: LayerNorm over channel dim + transpose (B,C,T) fp32 -> (B*T, C) bf16
// ---------------------------------------------------------------------------
__global__ __launch_bounds__(256) void ln_kernel(
    const float* __restrict__ x, const float* __restrict__ gamma,
    const float* __restrict__ beta, __hip_bfloat16* __restrict__ h)
{
    const int b  = blockIdx.x >> 6;
    const int t0 = (blockIdx.x & 63) * 32;
    const int tid = threadIdx.x;
    const int tl = tid & 31;
    const int part = tid >> 5;

    const float* xb = x + (size_t)b * CC * TT;

    float sum = 0.f, sq = 0.f;
    for (int ci = 0; ci < 64; ++ci) {
        int c = part * 64 + ci;
        float v = xb[(size_t)c * TT + t0 + tl];
        sum += v; sq += v * v;
    }
    __shared__ float sA[8][32], sB[8][32];
    sA[part][tl] = sum; sB[part][tl] = sq;
    __syncthreads();
    __shared__ float s_mu[32], s_rstd[32];
    if (part == 0) {
        float s = 0.f, q = 0.f;
        for (int p = 0; p < 8; ++p) { s += sA[p][tl]; q += sB[p][tl]; }
        float mu  = s * (1.0f / 512.0f);
        float var = q * (1.0f / 512.0f) - mu * mu;
        s_mu[tl] = mu;
        s_rstd[tl] = rsqrtf(var + 1e-5f);
    }
    __syncthreads();

    const float mu = s_mu[tl], rstd = s_rstd[tl];
    __shared__ __hip_bfloat16 tileT[32][72];

    for (int chunk = 0; chunk < 8; ++chunk) {
        int cb = chunk * 64 + part * 8;
        #pragma unroll
        for (int j = 0; j < 8; ++j) {
            int c = cb + j;
            float v = xb[(size_t)c * TT + t0 + tl];
            float nv = (v - mu) * rstd * gamma[c] + beta[c];
            tileT[tl][part * 8 + j] = __float2bfloat16(nv);
        }
        __syncthreads();
        int cl = tid & 63, tw = tid >> 6;
        #pragma unroll
        for (int k = 0; k < 8; ++k) {
            int t = tw + k * 4;
            h[((size_t)(b * TT + t0 + t)) * CC + chunk * 64 + cl] = tileT[t][cl];
        }
        __syncthreads();
    }
}

// ---------------------------------------------------------------------------
// Kernel 2: weight prepack: w (K,N) fp32 -> wt (N,K) bf16
// ---------------------------------------------------------------------------
__global__ __launch_bounds__(256) void prepack_w(
    const float* __restrict__ w, __hip_bfloat16* __restrict__ wt)
{
    __shared__ float tile[32][33];
    const int bx = blockIdx.x & 15;
    const int by = blockIdx.x >> 4;
    const int lx = threadIdx.x & 31, ly = threadIdx.x >> 5;
    #pragma unroll
    for (int i = 0; i < 4; ++i) {
        int k = by * 32 + ly + i * 8;
        tile[ly + i * 8][lx] = w[(size_t)k * 512 + bx * 32 + lx];
    }
    __syncthreads();
    #pragma unroll
    for (int i = 0; i < 4; ++i) {
        int n = bx * 32 + ly + i * 8;
        wt[(size_t)n * 512 + by * 32 + lx] = __float2bfloat16(tile[lx][ly + i * 8]);
    }
}

// ---------------------------------------------------------------------------
// Kernel 3: fused QKV GEMM.  Q,K -> (B,H,T,64);  V -> V^T (B,H,64,T)
// ---------------------------------------------------------------------------
__global__ __launch_bounds__(256) void qkv_gemm(
    const __hip_bfloat16* __restrict__ A,
    const __hip_bfloat16* __restrict__ wtq, const __hip_bfloat16* __restrict__ wtk,
    const __hip_bfloat16* __restrict__ wtv,
    const float* __restrict__ bq, const float* __restrict__ bk,
    const float* __restrict__ bv,
    __hip_bfloat16* __restrict__ qo, __hip_bfloat16* __restrict__ ko,
    __hip_bfloat16* __restrict__ vt)
{
    const int m0 = blockIdx.x * 128;
    const int n0 = blockIdx.y * 128;
    const __hip_bfloat16* WT; const float* bias; __hip_bfloat16* out;
    if (blockIdx.z == 0)      { WT = wtq; bias = bq; out = qo; }
    else if (blockIdx.z == 1) { WT = wtk; bias = bk; out = ko; }
    else                      { WT = wtv; bias = bv; out = vt; }

    __shared__ __hip_bfloat16 As[128][40];
    __shared__ __hip_bfloat16 Bs[128][40];
    __shared__ float eps[4][16][17];

    const int tid = threadIdx.x;
    const int wave = tid >> 6, lane = tid & 63;
    const int quad = lane >> 4, l16 = lane & 15;
    const int wy = wave >> 1, wx = wave & 1;

    f32x4 acc[4][4] = {};

    for (int kt = 0; kt < 512; kt += 32) {
        #pragma unroll
        for (int i = 0; i < 2; ++i) {
            int row = (tid >> 2) + i * 64;
            int kofs = (tid & 3) * 8;
            *reinterpret_cast<bf16x8*>(&As[row][kofs]) =
                *reinterpret_cast<const bf16x8*>(&A[(size_t)(m0 + row) * 512 + kt + kofs]);
            *reinterpret_cast<bf16x8*>(&Bs[row][kofs]) =
                *reinterpret_cast<const bf16x8*>(&WT[(size_t)(n0 + row) * 512 + kt + kofs]);
        }
        __syncthreads();
        bf16x8 af[4], bfr[4];
        #pragma unroll
        for (int mt = 0; mt < 4; ++mt)
            af[mt] = *reinterpret_cast<const bf16x8*>(&As[wy * 64 + mt * 16 + l16][quad * 8]);
        #pragma unroll
        for (int nt = 0; nt < 4; ++nt)
            bfr[nt] = *reinterpret_cast<const bf16x8*>(&Bs[wx * 64 + nt * 16 + l16][quad * 8]);
        #pragma unroll
        for (int mt = 0; mt < 4; ++mt)
            #pragma unroll
            for (int nt = 0; nt < 4; ++nt)
                acc[mt][nt] = __builtin_amdgcn_mfma_f32_16x16x32_bf16(
                    af[mt], bfr[nt], acc[mt][nt], 0, 0, 0);
        __syncthreads();
    }

    if (blockIdx.z != 2) {
        // direct layout: row t, col d
        #pragma unroll
        for (int nt = 0; nt < 4; ++nt) {
            int n = n0 + wx * 64 + nt * 16 + l16;
            int hh = n >> 6, di = n & 63;
            float bval = bias[n];
            #pragma unroll
            for (int mt = 0; mt < 4; ++mt) {
                #pragma unroll
                for (int r = 0; r < 4; ++r) {
                    int m = m0 + wy * 64 + mt * 16 + quad * 4 + r;
                    int b = m >> 11, t = m & 2047;
                    out[((size_t)((b * HH + hh) * TT + t)) * DH + di] =
                        __float2bfloat16(acc[mt][nt][r] + bval);
                }
            }
        }
    } else {
        // V^T: per-wave LDS transpose, write (B,H,64,T) coalesced over t
        #pragma unroll
        for (int mt = 0; mt < 4; ++mt) {
            int mbase = m0 + wy * 64 + mt * 16;
            #pragma unroll
            for (int nt = 0; nt < 4; ++nt) {
                int ncol = n0 + wx * 64 + nt * 16 + l16;
                float bval = bias[ncol];
                #pragma unroll
                for (int r = 0; r < 4; ++r)
                    eps[wave][quad * 4 + r][l16] = acc[mt][nt][r] + bval;
                #pragma unroll
                for (int pass = 0; pass < 4; ++pass) {
                    int nl = pass * 4 + quad;
                    int n = n0 + wx * 64 + nt * 16 + nl;
                    int hh = n >> 6, di = n & 63;
                    int m = mbase + l16;
                    int b = m >> 11, t = m & 2047;
                    out[((size_t)((b * HH + hh) * DH + di)) * TT + t] =
                        __float2bfloat16(eps[wave][l16][nl]);
                }
            }
        }
    }
}

// ---------------------------------------------------------------------------
// Kernel 4: causal flash attention (O^T formulation).
// Q,K: (B,H,T,64); Vt: (B,H,64,T); ctx: (B*T, 512) bf16
// block = 4 waves, 128 q rows; wave = 32 q rows (2 m-tiles); K-tile = 64.
// ---------------------------------------------------------------------------
__global__ __launch_bounds__(256) void attn_kernel(
    const __hip_bfloat16* __restrict__ Q, const __hip_bfloat16* __restrict__ K,
    const __hip_bfloat16* __restrict__ Vt, __hip_bfloat16* __restrict__ ctx)
{
    const int q0 = blockIdx.x * 128;
    const int bh = blockIdx.y;
    const __hip_bfloat16* Qb  = Q  + (size_t)bh * TT * DH;
    const __hip_bfloat16* Kb  = K  + (size_t)bh * TT * DH;
    const __hip_bfloat16* Vtb = Vt + (size_t)bh * DH * TT;

    const int tid = threadIdx.x, wave = tid >> 6, lane = tid & 63;
    const int quad = lane >> 4, l16 = lane & 15;

    __shared__ __hip_bfloat16 Ks[64][72];
    __shared__ __hip_bfloat16 Vts[64][72];   // [d][k]
    __shared__ __hip_bfloat16 Ps[4][32][72]; // per-wave P, [row][key]

    // Q fragments: qf[mt][st], A layout (m = qrow)
    bf16x8 qf[2][2];
    #pragma unroll
    for (int mt = 0; mt < 2; ++mt) {
        int qrow = q0 + wave * 32 + mt * 16 + l16;
        #pragma unroll
        for (int st = 0; st < 2; ++st)
            qf[mt][st] = *reinterpret_cast<const bf16x8*>(
                &Qb[(size_t)qrow * DH + st * 32 + quad * 8]);
    }

    bf16x8 ones;
    #pragma unroll
    for (int j = 0; j < 8; ++j) ones[j] = (__bf16)1.0f;

    f32x4 o_acc[4][2] = {};          // [dt][mt]: row=d, col=qrow(l16)
    float m_run[2][4];               // S-layout rows
    float l_run[2] = {0.f, 0.f};     // l16-indexed
    #pragma unroll
    for (int mt = 0; mt < 2; ++mt)
        #pragma unroll
        for (int r = 0; r < 4; ++r) m_run[mt][r] = -1e30f;

    const int kend = q0 + 128;
    for (int k0 = 0; k0 < kend; k0 += 64) {
        // stage K and Vt tiles
        {
            int rr = tid >> 3;
            int co = (tid & 7) * 8;
            #pragma unroll
            for (int i = 0; i < 2; ++i) {
                int r2 = rr + i * 32;
                *reinterpret_cast<bf16x8*>(&Ks[r2][co]) =
                    *reinterpret_cast<const bf16x8*>(&Kb[(size_t)(k0 + r2) * DH + co]);
                *reinterpret_cast<bf16x8*>(&Vts[r2][co]) =
                    *reinterpret_cast<const bf16x8*>(&Vtb[(size_t)r2 * TT + k0 + co]);
            }
        }
        __syncthreads();

        const bool active = (k0 <= q0 + wave * 32 + 31);
        if (active) {
            // S = Q K^T
            f32x4 s[2][4];
            #pragma unroll
            for (int nt = 0; nt < 4; ++nt) {
                bf16x8 kf0 = *reinterpret_cast<const bf16x8*>(&Ks[nt * 16 + l16][quad * 8]);
                bf16x8 kf1 = *reinterpret_cast<const bf16x8*>(&Ks[nt * 16 + l16][32 + quad * 8]);
                #pragma unroll
                for (int mt = 0; mt < 2; ++mt) {
                    f32x4 z = {};
                    z = __builtin_amdgcn_mfma_f32_16x16x32_bf16(qf[mt][0], kf0, z, 0, 0, 0);
                    z = __builtin_amdgcn_mfma_f32_16x16x32_bf16(qf[mt][1], kf1, z, 0, 0, 0);
                    s[mt][nt] = z;
                }
            }

            float av[2];
            #pragma unroll
            for (int mt = 0; mt < 2; ++mt) {
                const int qmtbase = q0 + wave * 32 + mt * 16 + quad * 4;
                const bool fullun = (k0 + 64 <= q0 + wave * 32 + mt * 16);
                float mtile[4] = {-1e30f, -1e30f, -1e30f, -1e30f};
                #pragma unroll
                for (int nt = 0; nt < 4; ++nt) {
                    int kg = k0 + nt * 16 + l16;
                    #pragma unroll
                    for (int r = 0; r < 4; ++r) {
                        float val = s[mt][nt][r] * 0.125f;
                        if (!fullun && kg > qmtbase + r) val = -1e9f;
                        s[mt][nt][r] = val;
                        mtile[r] = fmaxf(mtile[r], val);
                    }
                }
                float alphaS[4];
                #pragma unroll
                for (int r = 0; r < 4; ++r) {
                    float mv = mtile[r];
                    #pragma unroll
                    for (int off = 1; off < 16; off <<= 1)
                        mv = fmaxf(mv, __shfl_xor(mv, off, 64));
                    float mnew = fmaxf(m_run[mt][r], mv);
                    alphaS[r] = __expf(m_run[mt][r] - mnew);
                    m_run[mt][r] = mnew;
                    mtile[r] = mnew;
                }
                // P = exp(s - m) -> LDS (C layout)
                #pragma unroll
                for (int nt = 0; nt < 4; ++nt) {
                    #pragma unroll
                    for (int r = 0; r < 4; ++r) {
                        float p = __expf(s[mt][nt][r] - mtile[r]);
                        Ps[wave][mt * 16 + quad * 4 + r][nt * 16 + l16] = __float2bfloat16(p);
                    }
                }
                // transform alpha to l16-index: src quad = l16>>2, reg = l16&3
                int src = ((l16 >> 2) << 4) | l16;
                float a0 = __shfl(alphaS[0], src, 64);
                float a1 = __shfl(alphaS[1], src, 64);
                float a2 = __shfl(alphaS[2], src, 64);
                float a3 = __shfl(alphaS[3], src, 64);
                float a01 = (l16 & 1) ? a1 : a0;
                float a23 = (l16 & 1) ? a3 : a2;
                av[mt] = (l16 & 2) ? a23 : a01;
            }

            // rescale accumulators
            #pragma unroll
            for (int mt = 0; mt < 2; ++mt)
                #pragma unroll
                for (int dt = 0; dt < 4; ++dt)
                    #pragma unroll
                    for (int r = 0; r < 4; ++r)
                        o_acc[dt][mt][r] *= av[mt];

            // read P fragments (B layout for O^T: n=qrow, k=key)
            bf16x8 pf[2][2];
            #pragma unroll
            for (int mt = 0; mt < 2; ++mt)
                #pragma unroll
                for (int st = 0; st < 2; ++st)
                    pf[mt][st] = *reinterpret_cast<const bf16x8*>(
                        &Ps[wave][mt * 16 + l16][st * 32 + quad * 8]);

            // l update: rowsum via mfma(ones, P) -> cols = qrow (l16-indexed)
            #pragma unroll
            for (int mt = 0; mt < 2; ++mt) {
                f32x4 ls = {};
                ls = __builtin_amdgcn_mfma_f32_16x16x32_bf16(ones, pf[mt][0], ls, 0, 0, 0);
                ls = __builtin_amdgcn_mfma_f32_16x16x32_bf16(ones, pf[mt][1], ls, 0, 0, 0);
                l_run[mt] = av[mt] * l_run[mt] + ls[0];
            }

            // O^T += Vt * P^T
            #pragma unroll
            for (int dt = 0; dt < 4; ++dt) {
                bf16x8 vf0 = *reinterpret_cast<const bf16x8*>(&Vts[dt * 16 + l16][quad * 8]);
                bf16x8 vf1 = *reinterpret_cast<const bf16x8*>(&Vts[dt * 16 + l16][32 + quad * 8]);
                #pragma unroll
                for (int mt = 0; mt < 2; ++mt) {
                    o_acc[dt][mt] = __builtin_amdgcn_mfma_f32_16x16x32_bf16(
                        vf0, pf[mt][0], o_acc[dt][mt], 0, 0, 0);
                    o_acc[dt][mt] = __builtin_amdgcn_mfma_f32_16x16x32_bf16(
                        vf1, pf[mt][1], o_acc[dt][mt], 0, 0, 0);
                }
            }
        }
        __syncthreads();
    }

    // epilogue: ctx[(b*T + t)*512 + h*64 + d], t = l16-indexed col
    const int b = bh >> 3, hh = bh & 7;
    #pragma unroll
    for (int mt = 0; mt < 2; ++mt) {
        float inv = 1.0f / l_run[mt];
        int t = q0 + wave * 32 + mt * 16 + l16;
        #pragma unroll
        for (int dt = 0; dt < 4; ++dt) {
            bf16x4 pk;
            #pragma unroll
            for (int r = 0; r < 4; ++r)
                pk[r] = (__bf16)(o_acc[dt][mt][r] * inv);
            *reinterpret_cast<bf16x4*>(
                &ctx[((size_t)(b * TT + t)) * DD + hh * DH + dt * 16 + quad * 4]) = pk;
        }
    }
}

// ---------------------------------------------------------------------------
// Kernel 5: out-proj (swapped operands): D[c][t] = sum_d wto[c][d] * ctx[t][d]
// out(B,C,T) fp32 = x + D + bo;  coalesced epilogue (t along l16).
// ---------------------------------------------------------------------------
__global__ __launch_bounds__(256) void oproj_gemm(
    const __hip_bfloat16* __restrict__ WT, const __hip_bfloat16* __restrict__ Actx,
    const float* __restrict__ bo, const float* __restrict__ xres,
    float* __restrict__ outp)
{
    const int m0 = blockIdx.x * 128;   // c tile
    const int n0 = blockIdx.y * 128;   // token tile

    __shared__ __hip_bfloat16 As[128][40];
    __shared__ __hip_bfloat16 Bs[128][40];

    const int tid = threadIdx.x;
    const int wave = tid >> 6, lane = tid & 63;
    const int quad = lane >> 4, l16 = lane & 15;
    const int wy = wave >> 1, wx = wave & 1;

    f32x4 acc[4][4] = {};

    for (int kt = 0; kt < 512; kt += 32) {
        #pragma unroll
        for (int i = 0; i < 2; ++i) {
            int row = (tid >> 2) + i * 64;
            int kofs = (tid & 3) * 8;
            *reinterpret_cast<bf16x8*>(&As[row][kofs]) =
                *reinterpret_cast<const bf16x8*>(&WT[(size_t)(m0 + row) * 512 + kt + kofs]);
            *reinterpret_cast<bf16x8*>(&Bs[row][kofs]) =
                *reinterpret_cast<const bf16x8*>(&Actx[(size_t)(n0 + row) * 512 + kt + kofs]);
        }
        __syncthreads();
        bf16x8 af[4], bfr[4];
        #pragma unroll
        for (int mt = 0; mt < 4; ++mt)
            af[mt] = *reinterpret_cast<const bf16x8*>(&As[wy * 64 + mt * 16 + l16][quad * 8]);
        #pragma unroll
        for (int nt = 0; nt < 4; ++nt)
            bfr[nt] = *reinterpret_cast<const bf16x8*>(&Bs[wx * 64 + nt * 16 + l16][quad * 8]);
        #pragma unroll
        for (int mt = 0; mt < 4; ++mt)
            #pragma unroll
            for (int nt = 0; nt < 4; ++nt)
                acc[mt][nt] = __builtin_amdgcn_mfma_f32_16x16x32_bf16(
                    af[mt], bfr[nt], acc[mt][nt], 0, 0, 0);
        __syncthreads();
    }

    // C layout: row = c (quad*4+r), col = token (l16) -> coalesced fp32 stores
    #pragma unroll
    for (int mt = 0; mt < 4; ++mt) {
        #pragma unroll
        for (int nt = 0; nt < 4; ++nt) {
            int tg = n0 + wx * 64 + nt * 16 + l16;
            int b = tg >> 11, t = tg & 2047;
            #pragma unroll
            for (int r = 0; r < 4; ++r) {
                int c = m0 + wy * 64 + mt * 16 + quad * 4 + r;
                size_t oi = ((size_t)(b * CC + c)) * TT + t;
                outp[oi] = xres[oi] + acc[mt][nt][r] + bo[c];
            }
        }
    }
}

// ---------------------------------------------------------------------------
extern "C" void kernel_launch(void* const* d_in, const int* in_sizes, int n_in,
                              void* d_out, int out_size, void* d_ws, size_t ws_size,
                              hipStream_t stream)
{
    const float* x     = (const float*)d_in[0];
    const float* gamma = (const float*)d_in[1];
    const float* beta  = (const float*)d_in[2];
    const float* wq    = (const float*)d_in[3];
    const float* bq    = (const float*)d_in[4];
    const float* wk    = (const float*)d_in[5];
    const float* bk    = (const float*)d_in[6];
    const float* wv    = (const float*)d_in[7];
    const float* bv    = (const float*)d_in[8];
    const float* wo    = (const float*)d_in[9];
    const float* bo    = (const float*)d_in[10];
    float* out = (float*)d_out;

    char* ws = (char*)d_ws;
    const size_t sz_big = (size_t)BB * TT * DD * sizeof(__hip_bfloat16); // 16 MB
    __hip_bfloat16* hbf = (__hip_bfloat16*)ws; ws += sz_big;
    __hip_bfloat16* qb  = (__hip_bfloat16*)ws; ws += sz_big;
    __hip_bfloat16* kb  = (__hip_bfloat16*)ws; ws += sz_big;
    __hip_bfloat16* vtb = (__hip_bfloat16*)ws; ws += sz_big;
    __hip_bfloat16* ctx = (__hip_bfloat16*)ws; ws += sz_big;
    const size_t sz_w = (size_t)512 * 512 * sizeof(__hip_bfloat16);
    __hip_bfloat16* wtq = (__hip_bfloat16*)ws; ws += sz_w;
    __hip_bfloat16* wtk = (__hip_bfloat16*)ws; ws += sz_w;
    __hip_bfloat16* wtv = (__hip_bfloat16*)ws; ws += sz_w;
    __hip_bfloat16* wto = (__hip_bfloat16*)ws; ws += sz_w;

    prepack_w<<<256, 256, 0, stream>>>(wq, wtq);
    prepack_w<<<256, 256, 0, stream>>>(wk, wtk);
    prepack_w<<<256, 256, 0, stream>>>(wv, wtv);
    prepack_w<<<256, 256, 0, stream>>>(wo, wto);

    ln_kernel<<<BB * (TT / 32), 256, 0, stream>>>(x, gamma, beta, hbf);

    qkv_gemm<<<dim3(BB * TT / 128, DD / 128, 3), 256, 0, stream>>>(
        hbf, wtq, wtk, wtv, bq, bk, bv, qb, kb, vtb);

    attn_kernel<<<dim3(TT / 128, BB * HH), 256, 0, stream>>>(qb, kb, vtb, ctx);

    oproj_gemm<<<dim3(CC / 128, BB * TT / 128), 256, 0, stream>>>(
        wto, ctx, bo, x, out);
}

// Round 3
// 285.347 us; speedup vs baseline: 1.7210x; 1.3131x over previous
//
#include <hip/hip_runtime.h>
#include <hip/hip_bf16.h>

#define BB 8
#define TT 2048
#define CC 512
#define DD 512
#define HH 8
#define DH 64

typedef __bf16 bf16x8 __attribute__((ext_vector_type(8)));
typedef __bf16 bf16x4 __attribute__((ext_vector_type(4)));
typedef float  f32x4  __attribute__((ext_vector_type(4)));

static __device__ __forceinline__ bf16x8 concat4(bf16x4 a, bf16x4 b) {
    bf16x8 r;
    #pragma unroll
    for (int i = 0; i < 4; ++i) { r[i] = a[i]; r[i + 4] = b[i]; }
    return r;
}

// ---------------------------------------------------------------------------
// Kernel 1: LayerNorm over channel dim + transpose (B,C,T) fp32 -> (B*T, C) bf16
// ---------------------------------------------------------------------------
__global__ __launch_bounds__(256) void ln_kernel(
    const float* __restrict__ x, const float* __restrict__ gamma,
    const float* __restrict__ beta, __hip_bfloat16* __restrict__ h)
{
    const int b  = blockIdx.x >> 6;
    const int t0 = (blockIdx.x & 63) * 32;
    const int tid = threadIdx.x;
    const int tl = tid & 31;
    const int part = tid >> 5;

    const float* xb = x + (size_t)b * CC * TT;

    float sum = 0.f, sq = 0.f;
    for (int ci = 0; ci < 64; ++ci) {
        int c = part * 64 + ci;
        float v = xb[(size_t)c * TT + t0 + tl];
        sum += v; sq += v * v;
    }
    __shared__ float sA[8][32], sB[8][32];
    sA[part][tl] = sum; sB[part][tl] = sq;
    __syncthreads();
    __shared__ float s_mu[32], s_rstd[32];
    if (part == 0) {
        float s = 0.f, q = 0.f;
        for (int p = 0; p < 8; ++p) { s += sA[p][tl]; q += sB[p][tl]; }
        float mu  = s * (1.0f / 512.0f);
        float var = q * (1.0f / 512.0f) - mu * mu;
        s_mu[tl] = mu;
        s_rstd[tl] = rsqrtf(var + 1e-5f);
    }
    __syncthreads();

    const float mu = s_mu[tl], rstd = s_rstd[tl];
    __shared__ __hip_bfloat16 tileT[32][72];

    for (int chunk = 0; chunk < 8; ++chunk) {
        int cb = chunk * 64 + part * 8;
        #pragma unroll
        for (int j = 0; j < 8; ++j) {
            int c = cb + j;
            float v = xb[(size_t)c * TT + t0 + tl];
            float nv = (v - mu) * rstd * gamma[c] + beta[c];
            tileT[tl][part * 8 + j] = __float2bfloat16(nv);
        }
        __syncthreads();
        int cl = tid & 63, tw = tid >> 6;
        #pragma unroll
        for (int k = 0; k < 8; ++k) {
            int t = tw + k * 4;
            h[((size_t)(b * TT + t0 + t)) * CC + chunk * 64 + cl] = tileT[t][cl];
        }
        __syncthreads();
    }
}

// ---------------------------------------------------------------------------
// Kernel 2: weight prepack (all 4 weights in one launch):
// w (K,N) fp32 -> wt (N,K) bf16;  blockIdx.y selects the weight matrix.
// ---------------------------------------------------------------------------
__global__ __launch_bounds__(256) void prepack_w4(
    const float* __restrict__ w0, const float* __restrict__ w1,
    const float* __restrict__ w2, const float* __restrict__ w3,
    __hip_bfloat16* __restrict__ o0, __hip_bfloat16* __restrict__ o1,
    __hip_bfloat16* __restrict__ o2, __hip_bfloat16* __restrict__ o3)
{
    const float* w; __hip_bfloat16* wt;
    switch (blockIdx.y) {
        case 0: w = w0; wt = o0; break;
        case 1: w = w1; wt = o1; break;
        case 2: w = w2; wt = o2; break;
        default: w = w3; wt = o3; break;
    }
    __shared__ float tile[32][33];
    const int bx = blockIdx.x & 15;
    const int by = blockIdx.x >> 4;
    const int lx = threadIdx.x & 31, ly = threadIdx.x >> 5;
    #pragma unroll
    for (int i = 0; i < 4; ++i) {
        int k = by * 32 + ly + i * 8;
        tile[ly + i * 8][lx] = w[(size_t)k * 512 + bx * 32 + lx];
    }
    __syncthreads();
    #pragma unroll
    for (int i = 0; i < 4; ++i) {
        int n = bx * 32 + ly + i * 8;
        wt[(size_t)n * 512 + by * 32 + lx] = __float2bfloat16(tile[lx][ly + i * 8]);
    }
}

// ---------------------------------------------------------------------------
// Kernel 3: fused QKV GEMM.  Q (pre-scaled by log2e/8), K -> (B,H,T,64);
// V -> V^T (B,H,64,T)
// ---------------------------------------------------------------------------
__global__ __launch_bounds__(256) void qkv_gemm(
    const __hip_bfloat16* __restrict__ A,
    const __hip_bfloat16* __restrict__ wtq, const __hip_bfloat16* __restrict__ wtk,
    const __hip_bfloat16* __restrict__ wtv,
    const float* __restrict__ bq, const float* __restrict__ bk,
    const float* __restrict__ bv,
    __hip_bfloat16* __restrict__ qo, __hip_bfloat16* __restrict__ ko,
    __hip_bfloat16* __restrict__ vt)
{
    const int m0 = blockIdx.x * 128;
    const int n0 = blockIdx.y * 128;
    const __hip_bfloat16* WT; const float* bias; __hip_bfloat16* out;
    if (blockIdx.z == 0)      { WT = wtq; bias = bq; out = qo; }
    else if (blockIdx.z == 1) { WT = wtk; bias = bk; out = ko; }
    else                      { WT = wtv; bias = bv; out = vt; }
    // fold softmax scale (1/8) and log2(e) into Q
    const float sc = (blockIdx.z == 0) ? 0.18033688011112042f : 1.0f;

    __shared__ __hip_bfloat16 As[128][40];
    __shared__ __hip_bfloat16 Bs[128][40];
    __shared__ float eps[4][16][17];

    const int tid = threadIdx.x;
    const int wave = tid >> 6, lane = tid & 63;
    const int quad = lane >> 4, l16 = lane & 15;
    const int wy = wave >> 1, wx = wave & 1;

    f32x4 acc[4][4] = {};

    for (int kt = 0; kt < 512; kt += 32) {
        #pragma unroll
        for (int i = 0; i < 2; ++i) {
            int row = (tid >> 2) + i * 64;
            int kofs = (tid & 3) * 8;
            *reinterpret_cast<bf16x8*>(&As[row][kofs]) =
                *reinterpret_cast<const bf16x8*>(&A[(size_t)(m0 + row) * 512 + kt + kofs]);
            *reinterpret_cast<bf16x8*>(&Bs[row][kofs]) =
                *reinterpret_cast<const bf16x8*>(&WT[(size_t)(n0 + row) * 512 + kt + kofs]);
        }
        __syncthreads();
        bf16x8 af[4], bfr[4];
        #pragma unroll
        for (int mt = 0; mt < 4; ++mt)
            af[mt] = *reinterpret_cast<const bf16x8*>(&As[wy * 64 + mt * 16 + l16][quad * 8]);
        #pragma unroll
        for (int nt = 0; nt < 4; ++nt)
            bfr[nt] = *reinterpret_cast<const bf16x8*>(&Bs[wx * 64 + nt * 16 + l16][quad * 8]);
        #pragma unroll
        for (int mt = 0; mt < 4; ++mt)
            #pragma unroll
            for (int nt = 0; nt < 4; ++nt)
                acc[mt][nt] = __builtin_amdgcn_mfma_f32_16x16x32_bf16(
                    af[mt], bfr[nt], acc[mt][nt], 0, 0, 0);
        __syncthreads();
    }

    if (blockIdx.z != 2) {
        #pragma unroll
        for (int nt = 0; nt < 4; ++nt) {
            int n = n0 + wx * 64 + nt * 16 + l16;
            int hh = n >> 6, di = n & 63;
            float bval = bias[n];
            #pragma unroll
            for (int mt = 0; mt < 4; ++mt) {
                #pragma unroll
                for (int r = 0; r < 4; ++r) {
                    int m = m0 + wy * 64 + mt * 16 + quad * 4 + r;
                    int b = m >> 11, t = m & 2047;
                    out[((size_t)((b * HH + hh) * TT + t)) * DH + di] =
                        __float2bfloat16((acc[mt][nt][r] + bval) * sc);
                }
            }
        }
    } else {
        // V^T: per-wave LDS transpose, write (B,H,64,T) coalesced over t
        #pragma unroll
        for (int mt = 0; mt < 4; ++mt) {
            int mbase = m0 + wy * 64 + mt * 16;
            #pragma unroll
            for (int nt = 0; nt < 4; ++nt) {
                int ncol = n0 + wx * 64 + nt * 16 + l16;
                float bval = bias[ncol];
                #pragma unroll
                for (int r = 0; r < 4; ++r)
                    eps[wave][quad * 4 + r][l16] = acc[mt][nt][r] + bval;
                #pragma unroll
                for (int pass = 0; pass < 4; ++pass) {
                    int nl = pass * 4 + quad;
                    int n = n0 + wx * 64 + nt * 16 + nl;
                    int hh = n >> 6, di = n & 63;
                    int m = mbase + l16;
                    int b = m >> 11, t = m & 2047;
                    out[((size_t)((b * HH + hh) * DH + di)) * TT + t] =
                        __float2bfloat16(eps[wave][l16][nl]);
                }
            }
        }
    }
}

// ---------------------------------------------------------------------------
// Kernel 4: causal flash attention, S^T formulation, fixed-max softmax.
// Q (pre-scaled), K: (B,H,T,64); Vt: (B,H,64,T); ctx: (B*T, 512) bf16
// block = 4 waves x 32 q rows = 128 q; K-tile = 64.
// S^T = K*Q^T (A=K, B=Q) -> C layout: row(quad*4+r)=key, col(l16)=qrow.
// PV: O^T += Vt * P^T with K=32 MFMA whose k-slots are the permutation
// {j0..3 <-> key c*32+quad*4+j ; j4..7 <-> key c*32+16+quad*4+j}; P^T frag
// is built IN-REGISTER from the S^T accumulators (no LDS round-trip).
// ---------------------------------------------------------------------------
__global__ __launch_bounds__(256) void attn_kernel(
    const __hip_bfloat16* __restrict__ Q, const __hip_bfloat16* __restrict__ K,
    const __hip_bfloat16* __restrict__ Vt, __hip_bfloat16* __restrict__ ctx)
{
    const int q0 = (gridDim.x - 1 - blockIdx.x) * 128;   // longest blocks first
    const int bh = blockIdx.y;
    const __hip_bfloat16* Qb  = Q  + (size_t)bh * TT * DH;
    const __hip_bfloat16* Kb  = K  + (size_t)bh * TT * DH;
    const __hip_bfloat16* Vtb = Vt + (size_t)bh * DH * TT;

    const int tid = threadIdx.x, wave = tid >> 6, lane = tid & 63;
    const int quad = lane >> 4, l16 = lane & 15;

    __shared__ __hip_bfloat16 Ks[64][72];
    __shared__ __hip_bfloat16 Vts[64][72];   // [d][key]

    // Q fragments as B operand: B[n=qrow(l16)][k=d(quad*8+j)]
    bf16x8 qf[2][2];
    #pragma unroll
    for (int mt = 0; mt < 2; ++mt) {
        int qrow = q0 + wave * 32 + mt * 16 + l16;
        #pragma unroll
        for (int st = 0; st < 2; ++st)
            qf[mt][st] = *reinterpret_cast<const bf16x8*>(
                &Qb[(size_t)qrow * DH + st * 32 + quad * 8]);
    }

    f32x4 o_acc[4][2] = {};          // [dt][mt]: row=d, col=qrow(l16)
    float l_run[2] = {0.f, 0.f};     // per-lane partial (this quad's keys)

    const int kend = q0 + 128;
    for (int k0 = 0; k0 < kend; k0 += 64) {
        // stage K and Vt tiles
        {
            int rr = tid >> 3;
            int co = (tid & 7) * 8;
            #pragma unroll
            for (int i = 0; i < 2; ++i) {
                int r2 = rr + i * 32;
                *reinterpret_cast<bf16x8*>(&Ks[r2][co]) =
                    *reinterpret_cast<const bf16x8*>(&Kb[(size_t)(k0 + r2) * DH + co]);
                *reinterpret_cast<bf16x8*>(&Vts[r2][co]) =
                    *reinterpret_cast<const bf16x8*>(&Vtb[(size_t)r2 * TT + k0 + co]);
            }
        }
        __syncthreads();

        if (k0 <= q0 + wave * 32 + 31) {
            // S^T = K Q^T
            f32x4 s[2][4];
            #pragma unroll
            for (int nt = 0; nt < 4; ++nt) {
                bf16x8 kf0 = *reinterpret_cast<const bf16x8*>(&Ks[nt * 16 + l16][quad * 8]);
                bf16x8 kf1 = *reinterpret_cast<const bf16x8*>(&Ks[nt * 16 + l16][32 + quad * 8]);
                #pragma unroll
                for (int mt = 0; mt < 2; ++mt) {
                    f32x4 z = {};
                    z = __builtin_amdgcn_mfma_f32_16x16x32_bf16(kf0, qf[mt][0], z, 0, 0, 0);
                    z = __builtin_amdgcn_mfma_f32_16x16x32_bf16(kf1, qf[mt][1], z, 0, 0, 0);
                    s[mt][nt] = z;
                }
            }

            // P = exp2(s) (Q pre-scaled by log2e/8), causal mask, in-register
            bf16x4 pt[2][4];
            #pragma unroll
            for (int mt = 0; mt < 2; ++mt) {
                const int qrow = q0 + wave * 32 + mt * 16 + l16;
                const bool fullun = (k0 + 63 <= q0 + wave * 32 + mt * 16);
                float lsum = 0.f;
                #pragma unroll
                for (int nt = 0; nt < 4; ++nt) {
                    #pragma unroll
                    for (int r = 0; r < 4; ++r) {
                        float p = __builtin_amdgcn_exp2f(s[mt][nt][r]);
                        if (!fullun) {
                            int key = k0 + nt * 16 + quad * 4 + r;
                            if (key > qrow) p = 0.f;
                        }
                        lsum += p;
                        pt[mt][nt][r] = (__bf16)p;
                    }
                }
                l_run[mt] += lsum;
            }

            // O^T += Vt * P^T  (k-slot permutation; full-rate K=32)
            #pragma unroll
            for (int cp = 0; cp < 2; ++cp) {
                bf16x8 pfr[2];
                #pragma unroll
                for (int mt = 0; mt < 2; ++mt)
                    pfr[mt] = concat4(pt[mt][cp * 2], pt[mt][cp * 2 + 1]);
                #pragma unroll
                for (int dt = 0; dt < 4; ++dt) {
                    bf16x4 va = *reinterpret_cast<const bf16x4*>(
                        &Vts[dt * 16 + l16][cp * 32 + quad * 4]);
                    bf16x4 vb = *reinterpret_cast<const bf16x4*>(
                        &Vts[dt * 16 + l16][cp * 32 + 16 + quad * 4]);
                    bf16x8 vf = concat4(va, vb);
                    #pragma unroll
                    for (int mt = 0; mt < 2; ++mt)
                        o_acc[dt][mt] = __builtin_amdgcn_mfma_f32_16x16x32_bf16(
                            vf, pfr[mt], o_acc[dt][mt], 0, 0, 0);
                }
            }
        }
        __syncthreads();
    }

    // cross-quad l reduction (lanes quad*16+l16 share qrow=l16)
    float inv[2];
    #pragma unroll
    for (int mt = 0; mt < 2; ++mt) {
        float l = l_run[mt];
        l += __shfl_xor(l, 16, 64);
        l += __shfl_xor(l, 32, 64);
        inv[mt] = 1.0f / l;
    }

    // epilogue: ctx[(b*T + t)*512 + h*64 + d]
    const int b = bh >> 3, hh = bh & 7;
    #pragma unroll
    for (int mt = 0; mt < 2; ++mt) {
        int t = q0 + wave * 32 + mt * 16 + l16;
        #pragma unroll
        for (int dt = 0; dt < 4; ++dt) {
            bf16x4 pk;
            #pragma unroll
            for (int r = 0; r < 4; ++r)
                pk[r] = (__bf16)(o_acc[dt][mt][r] * inv[mt]);
            *reinterpret_cast<bf16x4*>(
                &ctx[((size_t)(b * TT + t)) * DD + hh * DH + dt * 16 + quad * 4]) = pk;
        }
    }
}

// ---------------------------------------------------------------------------
// Kernel 5: out-proj (swapped operands): D[c][t] = sum_d wto[c][d] * ctx[t][d]
// out(B,C,T) fp32 = x + D + bo;  coalesced epilogue (t along l16).
// ---------------------------------------------------------------------------
__global__ __launch_bounds__(256) void oproj_gemm(
    const __hip_bfloat16* __restrict__ WT, const __hip_bfloat16* __restrict__ Actx,
    const float* __restrict__ bo, const float* __restrict__ xres,
    float* __restrict__ outp)
{
    const int m0 = blockIdx.x * 128;   // c tile
    const int n0 = blockIdx.y * 128;   // token tile

    __shared__ __hip_bfloat16 As[128][40];
    __shared__ __hip_bfloat16 Bs[128][40];

    const int tid = threadIdx.x;
    const int wave = tid >> 6, lane = tid & 63;
    const int quad = lane >> 4, l16 = lane & 15;
    const int wy = wave >> 1, wx = wave & 1;

    f32x4 acc[4][4] = {};

    for (int kt = 0; kt < 512; kt += 32) {
        #pragma unroll
        for (int i = 0; i < 2; ++i) {
            int row = (tid >> 2) + i * 64;
            int kofs = (tid & 3) * 8;
            *reinterpret_cast<bf16x8*>(&As[row][kofs]) =
                *reinterpret_cast<const bf16x8*>(&WT[(size_t)(m0 + row) * 512 + kt + kofs]);
            *reinterpret_cast<bf16x8*>(&Bs[row][kofs]) =
                *reinterpret_cast<const bf16x8*>(&Actx[(size_t)(n0 + row) * 512 + kt + kofs]);
        }
        __syncthreads();
        bf16x8 af[4], bfr[4];
        #pragma unroll
        for (int mt = 0; mt < 4; ++mt)
            af[mt] = *reinterpret_cast<const bf16x8*>(&As[wy * 64 + mt * 16 + l16][quad * 8]);
        #pragma unroll
        for (int nt = 0; nt < 4; ++nt)
            bfr[nt] = *reinterpret_cast<const bf16x8*>(&Bs[wx * 64 + nt * 16 + l16][quad * 8]);
        #pragma unroll
        for (int mt = 0; mt < 4; ++mt)
            #pragma unroll
            for (int nt = 0; nt < 4; ++nt)
                acc[mt][nt] = __builtin_amdgcn_mfma_f32_16x16x32_bf16(
                    af[mt], bfr[nt], acc[mt][nt], 0, 0, 0);
        __syncthreads();
    }

    #pragma unroll
    for (int mt = 0; mt < 4; ++mt) {
        #pragma unroll
        for (int nt = 0; nt < 4; ++nt) {
            int tg = n0 + wx * 64 + nt * 16 + l16;
            int b = tg >> 11, t = tg & 2047;
            #pragma unroll
            for (int r = 0; r < 4; ++r) {
                int c = m0 + wy * 64 + mt * 16 + quad * 4 + r;
                size_t oi = ((size_t)(b * CC + c)) * TT + t;
                outp[oi] = xres[oi] + acc[mt][nt][r] + bo[c];
            }
        }
    }
}

// ---------------------------------------------------------------------------
extern "C" void kernel_launch(void* const* d_in, const int* in_sizes, int n_in,
                              void* d_out, int out_size, void* d_ws, size_t ws_size,
                              hipStream_t stream)
{
    const float* x     = (const float*)d_in[0];
    const float* gamma = (const float*)d_in[1];
    const float* beta  = (const float*)d_in[2];
    const float* wq    = (const float*)d_in[3];
    const float* bq    = (const float*)d_in[4];
    const float* wk    = (const float*)d_in[5];
    const float* bk    = (const float*)d_in[6];
    const float* wv    = (const float*)d_in[7];
    const float* bv    = (const float*)d_in[8];
    const float* wo    = (const float*)d_in[9];
    const float* bo    = (const float*)d_in[10];
    float* out = (float*)d_out;

    char* ws = (char*)d_ws;
    const size_t sz_big = (size_t)BB * TT * DD * sizeof(__hip_bfloat16); // 16 MB
    __hip_bfloat16* hbf = (__hip_bfloat16*)ws; ws += sz_big;
    __hip_bfloat16* qb  = (__hip_bfloat16*)ws; ws += sz_big;
    __hip_bfloat16* kb  = (__hip_bfloat16*)ws; ws += sz_big;
    __hip_bfloat16* vtb = (__hip_bfloat16*)ws; ws += sz_big;
    __hip_bfloat16* ctx = (__hip_bfloat16*)ws; ws += sz_big;
    const size_t sz_w = (size_t)512 * 512 * sizeof(__hip_bfloat16);
    __hip_bfloat16* wtq = (__hip_bfloat16*)ws; ws += sz_w;
    __hip_bfloat16* wtk = (__hip_bfloat16*)ws; ws += sz_w;
    __hip_bfloat16* wtv = (__hip_bfloat16*)ws; ws += sz_w;
    __hip_bfloat16* wto = (__hip_bfloat16*)ws; ws += sz_w;

    prepack_w4<<<dim3(256, 4), 256, 0, stream>>>(wq, wk, wv, wo,
                                                 wtq, wtk, wtv, wto);

    ln_kernel<<<BB * (TT / 32), 256, 0, stream>>>(x, gamma, beta, hbf);

    qkv_gemm<<<dim3(BB * TT / 128, DD / 128, 3), 256, 0, stream>>>(
        hbf, wtq, wtk, wtv, bq, bk, bv, qb, kb, vtb);

    attn_kernel<<<dim3(TT / 128, BB * HH), 256, 0, stream>>>(qb, kb, vtb, ctx);

    oproj_gemm<<<dim3(CC / 128, BB * TT / 128), 256, 0, stream>>>(
        wto, ctx, bo, x, out);
}

// Round 4
// 241.742 us; speedup vs baseline: 2.0315x; 1.1804x over previous
//
#include <hip/hip_runtime.h>
#include <hip/hip_bf16.h>

#define BB 8
#define TT 2048
#define CC 512
#define DD 512
#define HH 8
#define DH 64

typedef __bf16 bf16x8 __attribute__((ext_vector_type(8)));
typedef __bf16 bf16x4 __attribute__((ext_vector_type(4)));
typedef float  f32x4  __attribute__((ext_vector_type(4)));

static __device__ __forceinline__ bf16x8 concat4(bf16x4 a, bf16x4 b) {
    bf16x8 r;
    #pragma unroll
    for (int i = 0; i < 4; ++i) { r[i] = a[i]; r[i + 4] = b[i]; }
    return r;
}

// ---------------------------------------------------------------------------
// Kernel 1: LayerNorm over channel dim + transpose (B,C,T) fp32 -> (B*T, C) bf16
// ---------------------------------------------------------------------------
__global__ __launch_bounds__(256) void ln_kernel(
    const float* __restrict__ x, const float* __restrict__ gamma,
    const float* __restrict__ beta, __hip_bfloat16* __restrict__ h)
{
    const int b  = blockIdx.x >> 6;
    const int t0 = (blockIdx.x & 63) * 32;
    const int tid = threadIdx.x;
    const int tl = tid & 31;
    const int part = tid >> 5;

    const float* xb = x + (size_t)b * CC * TT;

    float sum = 0.f, sq = 0.f;
    for (int ci = 0; ci < 64; ++ci) {
        int c = part * 64 + ci;
        float v = xb[(size_t)c * TT + t0 + tl];
        sum += v; sq += v * v;
    }
    __shared__ float sA[8][32], sB[8][32];
    sA[part][tl] = sum; sB[part][tl] = sq;
    __syncthreads();
    __shared__ float s_mu[32], s_rstd[32];
    if (part == 0) {
        float s = 0.f, q = 0.f;
        for (int p = 0; p < 8; ++p) { s += sA[p][tl]; q += sB[p][tl]; }
        float mu  = s * (1.0f / 512.0f);
        float var = q * (1.0f / 512.0f) - mu * mu;
        s_mu[tl] = mu;
        s_rstd[tl] = rsqrtf(var + 1e-5f);
    }
    __syncthreads();

    const float mu = s_mu[tl], rstd = s_rstd[tl];
    __shared__ __hip_bfloat16 tileT[32][72];

    for (int chunk = 0; chunk < 8; ++chunk) {
        int cb = chunk * 64 + part * 8;
        #pragma unroll
        for (int j = 0; j < 8; ++j) {
            int c = cb + j;
            float v = xb[(size_t)c * TT + t0 + tl];
            float nv = (v - mu) * rstd * gamma[c] + beta[c];
            tileT[tl][part * 8 + j] = __float2bfloat16(nv);
        }
        __syncthreads();
        int cl = tid & 63, tw = tid >> 6;
        #pragma unroll
        for (int k = 0; k < 8; ++k) {
            int t = tw + k * 4;
            h[((size_t)(b * TT + t0 + t)) * CC + chunk * 64 + cl] = tileT[t][cl];
        }
        __syncthreads();
    }
}

// ---------------------------------------------------------------------------
// Kernel 2: weight prepack (all 4): w (K,N) fp32 -> wt (N,K) bf16
// ---------------------------------------------------------------------------
__global__ __launch_bounds__(256) void prepack_w4(
    const float* __restrict__ w0, const float* __restrict__ w1,
    const float* __restrict__ w2, const float* __restrict__ w3,
    __hip_bfloat16* __restrict__ o0, __hip_bfloat16* __restrict__ o1,
    __hip_bfloat16* __restrict__ o2, __hip_bfloat16* __restrict__ o3)
{
    const float* w; __hip_bfloat16* wt;
    switch (blockIdx.y) {
        case 0: w = w0; wt = o0; break;
        case 1: w = w1; wt = o1; break;
        case 2: w = w2; wt = o2; break;
        default: w = w3; wt = o3; break;
    }
    __shared__ float tile[32][33];
    const int bx = blockIdx.x & 15;
    const int by = blockIdx.x >> 4;
    const int lx = threadIdx.x & 31, ly = threadIdx.x >> 5;
    #pragma unroll
    for (int i = 0; i < 4; ++i) {
        int k = by * 32 + ly + i * 8;
        tile[ly + i * 8][lx] = w[(size_t)k * 512 + bx * 32 + lx];
    }
    __syncthreads();
    #pragma unroll
    for (int i = 0; i < 4; ++i) {
        int n = bx * 32 + ly + i * 8;
        wt[(size_t)n * 512 + by * 32 + lx] = __float2bfloat16(tile[lx][ly + i * 8]);
    }
}

// ---------------------------------------------------------------------------
// Kernel 3: fused QKV GEMM, double-buffered LDS + VGPR prefetch.
// Q (pre-scaled by log2e/8), K -> (B,H,T,64);  V -> V^T (B,H,64,T)
// ---------------------------------------------------------------------------
__global__ __launch_bounds__(256) void qkv_gemm(
    const __hip_bfloat16* __restrict__ A,
    const __hip_bfloat16* __restrict__ wtq, const __hip_bfloat16* __restrict__ wtk,
    const __hip_bfloat16* __restrict__ wtv,
    const float* __restrict__ bq, const float* __restrict__ bk,
    const float* __restrict__ bv,
    __hip_bfloat16* __restrict__ qo, __hip_bfloat16* __restrict__ ko,
    __hip_bfloat16* __restrict__ vt)
{
    const int m0 = blockIdx.x * 128;
    const int n0 = blockIdx.y * 128;
    const __hip_bfloat16* WT; const float* bias; __hip_bfloat16* out;
    if (blockIdx.z == 0)      { WT = wtq; bias = bq; out = qo; }
    else if (blockIdx.z == 1) { WT = wtk; bias = bk; out = ko; }
    else                      { WT = wtv; bias = bv; out = vt; }
    const float sc = (blockIdx.z == 0) ? 0.18033688011112042f : 1.0f;

    __shared__ __hip_bfloat16 As[2][128][40];
    __shared__ __hip_bfloat16 Bs[2][128][40];
    __shared__ float eps[4][16][17];

    const int tid = threadIdx.x;
    const int wave = tid >> 6, lane = tid & 63;
    const int quad = lane >> 4, l16 = lane & 15;
    const int wy = wave >> 1, wx = wave & 1;

    const int srow = tid >> 2;
    const int skof = (tid & 3) * 8;

    f32x4 acc[4][4] = {};
    bf16x8 areg[2], breg[2];

    // preload k-tile 0
    #pragma unroll
    for (int i = 0; i < 2; ++i) {
        int r = srow + i * 64;
        areg[i] = *reinterpret_cast<const bf16x8*>(&A[(size_t)(m0 + r) * 512 + skof]);
        breg[i] = *reinterpret_cast<const bf16x8*>(&WT[(size_t)(n0 + r) * 512 + skof]);
    }
    #pragma unroll
    for (int i = 0; i < 2; ++i) {
        int r = srow + i * 64;
        *reinterpret_cast<bf16x8*>(&As[0][r][skof]) = areg[i];
        *reinterpret_cast<bf16x8*>(&Bs[0][r][skof]) = breg[i];
    }
    __syncthreads();

    for (int kt = 0; kt < 512; kt += 32) {
        const int cur = (kt >> 5) & 1;
        const bool havenext = (kt + 32 < 512);
        if (havenext) {
            #pragma unroll
            for (int i = 0; i < 2; ++i) {
                int r = srow + i * 64;
                areg[i] = *reinterpret_cast<const bf16x8*>(
                    &A[(size_t)(m0 + r) * 512 + kt + 32 + skof]);
                breg[i] = *reinterpret_cast<const bf16x8*>(
                    &WT[(size_t)(n0 + r) * 512 + kt + 32 + skof]);
            }
        }
        bf16x8 af[4], bfr[4];
        #pragma unroll
        for (int mt = 0; mt < 4; ++mt)
            af[mt] = *reinterpret_cast<const bf16x8*>(&As[cur][wy * 64 + mt * 16 + l16][quad * 8]);
        #pragma unroll
        for (int nt = 0; nt < 4; ++nt)
            bfr[nt] = *reinterpret_cast<const bf16x8*>(&Bs[cur][wx * 64 + nt * 16 + l16][quad * 8]);
        #pragma unroll
        for (int mt = 0; mt < 4; ++mt)
            #pragma unroll
            for (int nt = 0; nt < 4; ++nt)
                acc[mt][nt] = __builtin_amdgcn_mfma_f32_16x16x32_bf16(
                    af[mt], bfr[nt], acc[mt][nt], 0, 0, 0);
        if (havenext) {
            #pragma unroll
            for (int i = 0; i < 2; ++i) {
                int r = srow + i * 64;
                *reinterpret_cast<bf16x8*>(&As[cur ^ 1][r][skof]) = areg[i];
                *reinterpret_cast<bf16x8*>(&Bs[cur ^ 1][r][skof]) = breg[i];
            }
        }
        __syncthreads();
    }

    if (blockIdx.z != 2) {
        #pragma unroll
        for (int nt = 0; nt < 4; ++nt) {
            int n = n0 + wx * 64 + nt * 16 + l16;
            int hh = n >> 6, di = n & 63;
            float bval = bias[n];
            #pragma unroll
            for (int mt = 0; mt < 4; ++mt) {
                #pragma unroll
                for (int r = 0; r < 4; ++r) {
                    int m = m0 + wy * 64 + mt * 16 + quad * 4 + r;
                    int b = m >> 11, t = m & 2047;
                    out[((size_t)((b * HH + hh) * TT + t)) * DH + di] =
                        __float2bfloat16((acc[mt][nt][r] + bval) * sc);
                }
            }
        }
    } else {
        // V^T: per-wave LDS transpose, write (B,H,64,T) coalesced over t
        #pragma unroll
        for (int mt = 0; mt < 4; ++mt) {
            int mbase = m0 + wy * 64 + mt * 16;
            #pragma unroll
            for (int nt = 0; nt < 4; ++nt) {
                int ncol = n0 + wx * 64 + nt * 16 + l16;
                float bval = bias[ncol];
                #pragma unroll
                for (int r = 0; r < 4; ++r)
                    eps[wave][quad * 4 + r][l16] = acc[mt][nt][r] + bval;
                #pragma unroll
                for (int pass = 0; pass < 4; ++pass) {
                    int nl = pass * 4 + quad;
                    int n = n0 + wx * 64 + nt * 16 + nl;
                    int hh = n >> 6, di = n & 63;
                    int m = mbase + l16;
                    int b = m >> 11, t = m & 2047;
                    out[((size_t)((b * HH + hh) * DH + di)) * TT + t] =
                        __float2bfloat16(eps[wave][l16][nl]);
                }
            }
        }
    }
}

// ---------------------------------------------------------------------------
// attn tile compute: S^T = K Q^T; P in-register; O^T += Vt P^T
// ---------------------------------------------------------------------------
static __device__ __forceinline__ void attn_tile(
    const __hip_bfloat16 (*Ksb)[72], const __hip_bfloat16 (*Vtsb)[72],
    int k0, int q0, int wave, int quad, int l16,
    const bf16x8 (&qf)[2][2], f32x4 (&o_acc)[4][2], float (&l_run)[2])
{
    f32x4 s[2][4];
    #pragma unroll
    for (int nt = 0; nt < 4; ++nt) {
        bf16x8 kf0 = *reinterpret_cast<const bf16x8*>(&Ksb[nt * 16 + l16][quad * 8]);
        bf16x8 kf1 = *reinterpret_cast<const bf16x8*>(&Ksb[nt * 16 + l16][32 + quad * 8]);
        #pragma unroll
        for (int mt = 0; mt < 2; ++mt) {
            f32x4 z = {};
            z = __builtin_amdgcn_mfma_f32_16x16x32_bf16(kf0, qf[mt][0], z, 0, 0, 0);
            z = __builtin_amdgcn_mfma_f32_16x16x32_bf16(kf1, qf[mt][1], z, 0, 0, 0);
            s[mt][nt] = z;
        }
    }
    bf16x4 pt[2][4];
    #pragma unroll
    for (int mt = 0; mt < 2; ++mt) {
        const int qrow = q0 + wave * 32 + mt * 16 + l16;
        const bool fullun = (k0 + 63 <= q0 + wave * 32 + mt * 16);
        float lsum = 0.f;
        #pragma unroll
        for (int nt = 0; nt < 4; ++nt) {
            #pragma unroll
            for (int r = 0; r < 4; ++r) {
                float p = __builtin_amdgcn_exp2f(s[mt][nt][r]);
                if (!fullun) {
                    int key = k0 + nt * 16 + quad * 4 + r;
                    if (key > qrow) p = 0.f;
                }
                lsum += p;
                pt[mt][nt][r] = (__bf16)p;
            }
        }
        l_run[mt] += lsum;
    }
    #pragma unroll
    for (int cp = 0; cp < 2; ++cp) {
        bf16x8 pfr[2];
        #pragma unroll
        for (int mt = 0; mt < 2; ++mt)
            pfr[mt] = concat4(pt[mt][cp * 2], pt[mt][cp * 2 + 1]);
        #pragma unroll
        for (int dt = 0; dt < 4; ++dt) {
            bf16x4 va = *reinterpret_cast<const bf16x4*>(
                &Vtsb[dt * 16 + l16][cp * 32 + quad * 4]);
            bf16x4 vb = *reinterpret_cast<const bf16x4*>(
                &Vtsb[dt * 16 + l16][cp * 32 + 16 + quad * 4]);
            bf16x8 vf = concat4(va, vb);
            #pragma unroll
            for (int mt = 0; mt < 2; ++mt)
                o_acc[dt][mt] = __builtin_amdgcn_mfma_f32_16x16x32_bf16(
                    vf, pfr[mt], o_acc[dt][mt], 0, 0, 0);
        }
    }
}

// ---------------------------------------------------------------------------
// Kernel 4: causal flash attention, pair-balanced (uniform work/block),
// double-buffered LDS + VGPR prefetch.
// Block xi handles q-tiles {xi, 15-xi} sharing one k-stream. Grid (8, 64).
// ---------------------------------------------------------------------------
__global__ __launch_bounds__(256, 2) void attn_kernel(
    const __hip_bfloat16* __restrict__ Q, const __hip_bfloat16* __restrict__ K,
    const __hip_bfloat16* __restrict__ Vt, __hip_bfloat16* __restrict__ ctx)
{
    const int xi = blockIdx.x;
    const int bh = blockIdx.y;
    const int q0h = (15 - xi) * 128;
    const int q0l = xi * 128;
    const __hip_bfloat16* Qb  = Q  + (size_t)bh * TT * DH;
    const __hip_bfloat16* Kb  = K  + (size_t)bh * TT * DH;
    const __hip_bfloat16* Vtb = Vt + (size_t)bh * DH * TT;

    const int tid = threadIdx.x, wave = tid >> 6, lane = tid & 63;
    const int quad = lane >> 4, l16 = lane & 15;

    __shared__ __hip_bfloat16 Ks[2][64][72];
    __shared__ __hip_bfloat16 Vts[2][64][72];

    bf16x8 qfh[2][2], qfl[2][2];
    #pragma unroll
    for (int mt = 0; mt < 2; ++mt) {
        int rh = q0h + wave * 32 + mt * 16 + l16;
        int rl = q0l + wave * 32 + mt * 16 + l16;
        #pragma unroll
        for (int st = 0; st < 2; ++st) {
            qfh[mt][st] = *reinterpret_cast<const bf16x8*>(
                &Qb[(size_t)rh * DH + st * 32 + quad * 8]);
            qfl[mt][st] = *reinterpret_cast<const bf16x8*>(
                &Qb[(size_t)rl * DH + st * 32 + quad * 8]);
        }
    }

    f32x4 oh[4][2] = {}, ol[4][2] = {};
    float lh[2] = {0.f, 0.f}, ll[2] = {0.f, 0.f};

    const int rr = tid >> 3;          // 0..31
    const int co = (tid & 7) * 8;

    bf16x8 kreg[2], vreg[2];
    #pragma unroll
    for (int i = 0; i < 2; ++i) {
        int r2 = rr + i * 32;
        kreg[i] = *reinterpret_cast<const bf16x8*>(&Kb[(size_t)r2 * DH + co]);
        vreg[i] = *reinterpret_cast<const bf16x8*>(&Vtb[(size_t)r2 * TT + co]);
    }
    #pragma unroll
    for (int i = 0; i < 2; ++i) {
        int r2 = rr + i * 32;
        *reinterpret_cast<bf16x8*>(&Ks[0][r2][co]) = kreg[i];
        *reinterpret_cast<bf16x8*>(&Vts[0][r2][co]) = vreg[i];
    }
    __syncthreads();

    const int nsteps = q0h / 64 + 2;
    for (int step = 0; step < nsteps; ++step) {
        const int k0 = step * 64;
        const int cur = step & 1;
        const bool havenext = (step + 1 < nsteps);
        if (havenext) {
            const int kn = k0 + 64;
            #pragma unroll
            for (int i = 0; i < 2; ++i) {
                int r2 = rr + i * 32;
                kreg[i] = *reinterpret_cast<const bf16x8*>(
                    &Kb[(size_t)(kn + r2) * DH + co]);
                vreg[i] = *reinterpret_cast<const bf16x8*>(
                    &Vtb[(size_t)r2 * TT + kn + co]);
            }
        }
        if (k0 <= q0h + wave * 32 + 31)
            attn_tile(Ks[cur], Vts[cur], k0, q0h, wave, quad, l16, qfh, oh, lh);
        if (k0 <= q0l + wave * 32 + 31)
            attn_tile(Ks[cur], Vts[cur], k0, q0l, wave, quad, l16, qfl, ol, ll);
        if (havenext) {
            const int nxt = cur ^ 1;
            #pragma unroll
            for (int i = 0; i < 2; ++i) {
                int r2 = rr + i * 32;
                *reinterpret_cast<bf16x8*>(&Ks[nxt][r2][co]) = kreg[i];
                *reinterpret_cast<bf16x8*>(&Vts[nxt][r2][co]) = vreg[i];
            }
        }
        __syncthreads();
    }

    float invh[2], invl[2];
    #pragma unroll
    for (int mt = 0; mt < 2; ++mt) {
        float a = lh[mt];
        a += __shfl_xor(a, 16, 64); a += __shfl_xor(a, 32, 64);
        invh[mt] = 1.0f / a;
        float c = ll[mt];
        c += __shfl_xor(c, 16, 64); c += __shfl_xor(c, 32, 64);
        invl[mt] = 1.0f / c;
    }

    const int b = bh >> 3, hh = bh & 7;
    #pragma unroll
    for (int mt = 0; mt < 2; ++mt) {
        int th = q0h + wave * 32 + mt * 16 + l16;
        int tl2 = q0l + wave * 32 + mt * 16 + l16;
        #pragma unroll
        for (int dt = 0; dt < 4; ++dt) {
            bf16x4 pa, pb;
            #pragma unroll
            for (int r = 0; r < 4; ++r) {
                pa[r] = (__bf16)(oh[dt][mt][r] * invh[mt]);
                pb[r] = (__bf16)(ol[dt][mt][r] * invl[mt]);
            }
            *reinterpret_cast<bf16x4*>(
                &ctx[((size_t)(b * TT + th)) * DD + hh * DH + dt * 16 + quad * 4]) = pa;
            *reinterpret_cast<bf16x4*>(
                &ctx[((size_t)(b * TT + tl2)) * DD + hh * DH + dt * 16 + quad * 4]) = pb;
        }
    }
}

// ---------------------------------------------------------------------------
// Kernel 5: out-proj (swapped operands), double-buffered:
// D[c][t] = sum_d wto[c][d] * ctx[t][d];  out = x + D + bo (coalesced t).
// ---------------------------------------------------------------------------
__global__ __launch_bounds__(256) void oproj_gemm(
    const __hip_bfloat16* __restrict__ WT, const __hip_bfloat16* __restrict__ Actx,
    const float* __restrict__ bo, const float* __restrict__ xres,
    float* __restrict__ outp)
{
    const int m0 = blockIdx.x * 128;   // c tile
    const int n0 = blockIdx.y * 128;   // token tile

    __shared__ __hip_bfloat16 As[2][128][40];
    __shared__ __hip_bfloat16 Bs[2][128][40];

    const int tid = threadIdx.x;
    const int wave = tid >> 6, lane = tid & 63;
    const int quad = lane >> 4, l16 = lane & 15;
    const int wy = wave >> 1, wx = wave & 1;

    const int srow = tid >> 2;
    const int skof = (tid & 3) * 8;

    f32x4 acc[4][4] = {};
    bf16x8 areg[2], breg[2];

    #pragma unroll
    for (int i = 0; i < 2; ++i) {
        int r = srow + i * 64;
        areg[i] = *reinterpret_cast<const bf16x8*>(&WT[(size_t)(m0 + r) * 512 + skof]);
        breg[i] = *reinterpret_cast<const bf16x8*>(&Actx[(size_t)(n0 + r) * 512 + skof]);
    }
    #pragma unroll
    for (int i = 0; i < 2; ++i) {
        int r = srow + i * 64;
        *reinterpret_cast<bf16x8*>(&As[0][r][skof]) = areg[i];
        *reinterpret_cast<bf16x8*>(&Bs[0][r][skof]) = breg[i];
    }
    __syncthreads();

    for (int kt = 0; kt < 512; kt += 32) {
        const int cur = (kt >> 5) & 1;
        const bool havenext = (kt + 32 < 512);
        if (havenext) {
            #pragma unroll
            for (int i = 0; i < 2; ++i) {
                int r = srow + i * 64;
                areg[i] = *reinterpret_cast<const bf16x8*>(
                    &WT[(size_t)(m0 + r) * 512 + kt + 32 + skof]);
                breg[i] = *reinterpret_cast<const bf16x8*>(
                    &Actx[(size_t)(n0 + r) * 512 + kt + 32 + skof]);
            }
        }
        bf16x8 af[4], bfr[4];
        #pragma unroll
        for (int mt = 0; mt < 4; ++mt)
            af[mt] = *reinterpret_cast<const bf16x8*>(&As[cur][wy * 64 + mt * 16 + l16][quad * 8]);
        #pragma unroll
        for (int nt = 0; nt < 4; ++nt)
            bfr[nt] = *reinterpret_cast<const bf16x8*>(&Bs[cur][wx * 64 + nt * 16 + l16][quad * 8]);
        #pragma unroll
        for (int mt = 0; mt < 4; ++mt)
            #pragma unroll
            for (int nt = 0; nt < 4; ++nt)
                acc[mt][nt] = __builtin_amdgcn_mfma_f32_16x16x32_bf16(
                    af[mt], bfr[nt], acc[mt][nt], 0, 0, 0);
        if (havenext) {
            #pragma unroll
            for (int i = 0; i < 2; ++i) {
                int r = srow + i * 64;
                *reinterpret_cast<bf16x8*>(&As[cur ^ 1][r][skof]) = areg[i];
                *reinterpret_cast<bf16x8*>(&Bs[cur ^ 1][r][skof]) = breg[i];
            }
        }
        __syncthreads();
    }

    #pragma unroll
    for (int mt = 0; mt < 4; ++mt) {
        #pragma unroll
        for (int nt = 0; nt < 4; ++nt) {
            int tg = n0 + wx * 64 + nt * 16 + l16;
            int b = tg >> 11, t = tg & 2047;
            #pragma unroll
            for (int r = 0; r < 4; ++r) {
                int c = m0 + wy * 64 + mt * 16 + quad * 4 + r;
                size_t oi = ((size_t)(b * CC + c)) * TT + t;
                outp[oi] = xres[oi] + acc[mt][nt][r] + bo[c];
            }
        }
    }
}

// ---------------------------------------------------------------------------
extern "C" void kernel_launch(void* const* d_in, const int* in_sizes, int n_in,
                              void* d_out, int out_size, void* d_ws, size_t ws_size,
                              hipStream_t stream)
{
    const float* x     = (const float*)d_in[0];
    const float* gamma = (const float*)d_in[1];
    const float* beta  = (const float*)d_in[2];
    const float* wq    = (const float*)d_in[3];
    const float* bq    = (const float*)d_in[4];
    const float* wk    = (const float*)d_in[5];
    const float* bk    = (const float*)d_in[6];
    const float* wv    = (const float*)d_in[7];
    const float* bv    = (const float*)d_in[8];
    const float* wo    = (const float*)d_in[9];
    const float* bo    = (const float*)d_in[10];
    float* out = (float*)d_out;

    char* ws = (char*)d_ws;
    const size_t sz_big = (size_t)BB * TT * DD * sizeof(__hip_bfloat16); // 16 MB
    __hip_bfloat16* hbf = (__hip_bfloat16*)ws; ws += sz_big;
    __hip_bfloat16* qb  = (__hip_bfloat16*)ws; ws += sz_big;
    __hip_bfloat16* kb  = (__hip_bfloat16*)ws; ws += sz_big;
    __hip_bfloat16* vtb = (__hip_bfloat16*)ws; ws += sz_big;
    __hip_bfloat16* ctx = (__hip_bfloat16*)ws; ws += sz_big;
    const size_t sz_w = (size_t)512 * 512 * sizeof(__hip_bfloat16);
    __hip_bfloat16* wtq = (__hip_bfloat16*)ws; ws += sz_w;
    __hip_bfloat16* wtk = (__hip_bfloat16*)ws; ws += sz_w;
    __hip_bfloat16* wtv = (__hip_bfloat16*)ws; ws += sz_w;
    __hip_bfloat16* wto = (__hip_bfloat16*)ws; ws += sz_w;

    prepack_w4<<<dim3(256, 4), 256, 0, stream>>>(wq, wk, wv, wo,
                                                 wtq, wtk, wtv, wto);

    ln_kernel<<<BB * (TT / 32), 256, 0, stream>>>(x, gamma, beta, hbf);

    qkv_gemm<<<dim3(BB * TT / 128, DD / 128, 3), 256, 0, stream>>>(
        hbf, wtq, wtk, wtv, bq, bk, bv, qb, kb, vtb);

    attn_kernel<<<dim3(8, BB * HH), 256, 0, stream>>>(qb, kb, vtb, ctx);

    oproj_gemm<<<dim3(CC / 128, BB * TT / 128), 256, 0, stream>>>(
        wto, ctx, bo, x, out);
}

// Round 5
// 240.550 us; speedup vs baseline: 2.0415x; 1.0050x over previous
//
#include <hip/hip_runtime.h>
#include <hip/hip_bf16.h>

#define BB 8
#define TT 2048
#define CC 512
#define DD 512
#define HH 8
#define DH 64

typedef __bf16 bf16x8 __attribute__((ext_vector_type(8)));
typedef __bf16 bf16x4 __attribute__((ext_vector_type(4)));
typedef float  f32x4  __attribute__((ext_vector_type(4)));

static __device__ __forceinline__ bf16x8 concat4(bf16x4 a, bf16x4 b) {
    bf16x8 r;
    #pragma unroll
    for (int i = 0; i < 4; ++i) { r[i] = a[i]; r[i + 4] = b[i]; }
    return r;
}

// async global->LDS, 16B per lane; lds base must be wave-uniform
static __device__ __forceinline__ void async_ld16(const void* g, void* l) {
    __builtin_amdgcn_global_load_lds(
        (const __attribute__((address_space(1))) void*)g,
        (__attribute__((address_space(3))) void*)l, 16, 0, 0);
}

// ---------------------------------------------------------------------------
// Kernel 1: LayerNorm + transpose (B,C,T) fp32 -> (B*T, C) bf16.
// x tile cached in LDS: read x once (was twice).
// ---------------------------------------------------------------------------
__global__ __launch_bounds__(256) void ln_kernel(
    const float* __restrict__ x, const float* __restrict__ gamma,
    const float* __restrict__ beta, __hip_bfloat16* __restrict__ h)
{
    const int b  = blockIdx.x >> 6;
    const int t0 = (blockIdx.x & 63) * 32;
    const int tid = threadIdx.x;
    const int tl = tid & 31;
    const int part = tid >> 5;

    const float* xb = x + (size_t)b * CC * TT;

    __shared__ float xs[512][32];    // 64 KB
    float sum = 0.f, sq = 0.f;
    #pragma unroll 8
    for (int ci = 0; ci < 64; ++ci) {
        int c = part * 64 + ci;
        float v = xb[(size_t)c * TT + t0 + tl];
        xs[c][tl] = v;
        sum += v; sq += v * v;
    }
    __shared__ float sA[8][32], sB[8][32];
    sA[part][tl] = sum; sB[part][tl] = sq;
    __syncthreads();
    __shared__ float s_mu[32], s_rstd[32];
    if (part == 0) {
        float s = 0.f, q = 0.f;
        for (int p = 0; p < 8; ++p) { s += sA[p][tl]; q += sB[p][tl]; }
        float mu  = s * (1.0f / 512.0f);
        float var = q * (1.0f / 512.0f) - mu * mu;
        s_mu[tl] = mu;
        s_rstd[tl] = rsqrtf(var + 1e-5f);
    }
    __syncthreads();

    const float mu = s_mu[tl], rstd = s_rstd[tl];
    __shared__ __hip_bfloat16 tileT[32][72];

    for (int chunk = 0; chunk < 8; ++chunk) {
        int cb = chunk * 64 + part * 8;
        #pragma unroll
        for (int j = 0; j < 8; ++j) {
            int c = cb + j;
            float nv = (xs[c][tl] - mu) * rstd * gamma[c] + beta[c];
            tileT[tl][part * 8 + j] = __float2bfloat16(nv);
        }
        __syncthreads();
        int cl = tid & 63, tw = tid >> 6;
        #pragma unroll
        for (int k = 0; k < 8; ++k) {
            int t = tw + k * 4;
            h[((size_t)(b * TT + t0 + t)) * CC + chunk * 64 + cl] = tileT[t][cl];
        }
        __syncthreads();
    }
}

// ---------------------------------------------------------------------------
// Kernel 2: weight prepack (all 4): w (K,N) fp32 -> wt (N,K) bf16
// ---------------------------------------------------------------------------
__global__ __launch_bounds__(256) void prepack_w4(
    const float* __restrict__ w0, const float* __restrict__ w1,
    const float* __restrict__ w2, const float* __restrict__ w3,
    __hip_bfloat16* __restrict__ o0, __hip_bfloat16* __restrict__ o1,
    __hip_bfloat16* __restrict__ o2, __hip_bfloat16* __restrict__ o3)
{
    const float* w; __hip_bfloat16* wt;
    switch (blockIdx.y) {
        case 0: w = w0; wt = o0; break;
        case 1: w = w1; wt = o1; break;
        case 2: w = w2; wt = o2; break;
        default: w = w3; wt = o3; break;
    }
    __shared__ float tile[32][33];
    const int bx = blockIdx.x & 15;
    const int by = blockIdx.x >> 4;
    const int lx = threadIdx.x & 31, ly = threadIdx.x >> 5;
    #pragma unroll
    for (int i = 0; i < 4; ++i) {
        int k = by * 32 + ly + i * 8;
        tile[ly + i * 8][lx] = w[(size_t)k * 512 + bx * 32 + lx];
    }
    __syncthreads();
    #pragma unroll
    for (int i = 0; i < 4; ++i) {
        int n = bx * 32 + ly + i * 8;
        wt[(size_t)n * 512 + by * 32 + lx] = __float2bfloat16(tile[lx][ly + i * 8]);
    }
}

// ---------------------------------------------------------------------------
// Kernel 3: fused QKV GEMM with global_load_lds (width 16) staging.
// Q (pre-scaled by log2e/8), K -> (B,H,T,64);  V -> V^T (B,H,64,T)
// Unpadded LDS [128][32] (64 B rows), m97-style 2-barrier K-loop.
// ---------------------------------------------------------------------------
__global__ __launch_bounds__(256) void qkv_gemm(
    const __hip_bfloat16* __restrict__ A,
    const __hip_bfloat16* __restrict__ wtq, const __hip_bfloat16* __restrict__ wtk,
    const __hip_bfloat16* __restrict__ wtv,
    const float* __restrict__ bq, const float* __restrict__ bk,
    const float* __restrict__ bv,
    __hip_bfloat16* __restrict__ qo, __hip_bfloat16* __restrict__ ko,
    __hip_bfloat16* __restrict__ vt)
{
    const int m0 = blockIdx.x * 128;
    const int n0 = blockIdx.y * 128;
    const __hip_bfloat16* WT; const float* bias; __hip_bfloat16* out;
    if (blockIdx.z == 0)      { WT = wtq; bias = bq; out = qo; }
    else if (blockIdx.z == 1) { WT = wtk; bias = bk; out = ko; }
    else                      { WT = wtv; bias = bv; out = vt; }
    const float sc = (blockIdx.z == 0) ? 0.18033688011112042f : 1.0f;

    __shared__ __hip_bfloat16 As[128][32];
    __shared__ __hip_bfloat16 Bs[128][32];
    __shared__ float eps[4][16][17];

    const int tid = threadIdx.x;
    const int wave = tid >> 6, lane = tid & 63;
    const int quad = lane >> 4, l16 = lane & 15;
    const int wy = wave >> 1, wx = wave & 1;

    const int lrow = lane >> 2;          // 0..15 within a 16-row issue
    const int lcol = (lane & 3) * 8;     // element offset (16 B)

    f32x4 acc[4][4] = {};

    for (int kt = 0; kt < 512; kt += 32) {
        #pragma unroll
        for (int i = 0; i < 2; ++i) {
            int rbase = wave * 32 + i * 16;
            int row = rbase + lrow;
            async_ld16(&A[(size_t)(m0 + row) * 512 + kt + lcol], &As[rbase][0]);
            async_ld16(&WT[(size_t)(n0 + row) * 512 + kt + lcol], &Bs[rbase][0]);
        }
        __syncthreads();
        bf16x8 af[4], bfr[4];
        #pragma unroll
        for (int mt = 0; mt < 4; ++mt)
            af[mt] = *reinterpret_cast<const bf16x8*>(&As[wy * 64 + mt * 16 + l16][quad * 8]);
        #pragma unroll
        for (int nt = 0; nt < 4; ++nt)
            bfr[nt] = *reinterpret_cast<const bf16x8*>(&Bs[wx * 64 + nt * 16 + l16][quad * 8]);
        #pragma unroll
        for (int mt = 0; mt < 4; ++mt)
            #pragma unroll
            for (int nt = 0; nt < 4; ++nt)
                acc[mt][nt] = __builtin_amdgcn_mfma_f32_16x16x32_bf16(
                    af[mt], bfr[nt], acc[mt][nt], 0, 0, 0);
        __syncthreads();
    }

    if (blockIdx.z != 2) {
        #pragma unroll
        for (int nt = 0; nt < 4; ++nt) {
            int n = n0 + wx * 64 + nt * 16 + l16;
            int hh = n >> 6, di = n & 63;
            float bval = bias[n];
            #pragma unroll
            for (int mt = 0; mt < 4; ++mt) {
                #pragma unroll
                for (int r = 0; r < 4; ++r) {
                    int m = m0 + wy * 64 + mt * 16 + quad * 4 + r;
                    int b = m >> 11, t = m & 2047;
                    out[((size_t)((b * HH + hh) * TT + t)) * DH + di] =
                        __float2bfloat16((acc[mt][nt][r] + bval) * sc);
                }
            }
        }
    } else {
        // V^T: per-wave LDS transpose, write (B,H,64,T) coalesced over t
        #pragma unroll
        for (int mt = 0; mt < 4; ++mt) {
            int mbase = m0 + wy * 64 + mt * 16;
            #pragma unroll
            for (int nt = 0; nt < 4; ++nt) {
                int ncol = n0 + wx * 64 + nt * 16 + l16;
                float bval = bias[ncol];
                #pragma unroll
                for (int r = 0; r < 4; ++r)
                    eps[wave][quad * 4 + r][l16] = acc[mt][nt][r] + bval;
                #pragma unroll
                for (int pass = 0; pass < 4; ++pass) {
                    int nl = pass * 4 + quad;
                    int n = n0 + wx * 64 + nt * 16 + nl;
                    int hh = n >> 6, di = n & 63;
                    int m = mbase + l16;
                    int b = m >> 11, t = m & 2047;
                    out[((size_t)((b * HH + hh) * DH + di)) * TT + t] =
                        __float2bfloat16(eps[wave][l16][nl]);
                }
            }
        }
    }
}

// ---------------------------------------------------------------------------
// attn: exp/mask phase (wave-uniform branch between masked/unmasked)
// ---------------------------------------------------------------------------
static __device__ __forceinline__ void exp_phase(
    const f32x4 (&s)[2][4], bf16x4 (&pt)[2][4], float (&lr)[2],
    int k0, int q0, int wave, int quad, int l16)
{
    #pragma unroll
    for (int mt = 0; mt < 2; ++mt) {
        float lsum = 0.f;
        if (k0 + 63 <= q0 + wave * 32 + mt * 16) {
            // interior tile: no masking
            #pragma unroll
            for (int nt = 0; nt < 4; ++nt) {
                #pragma unroll
                for (int r = 0; r < 4; ++r) {
                    float p = __builtin_amdgcn_exp2f(s[mt][nt][r]);
                    lsum += p;
                    pt[mt][nt][r] = (__bf16)p;
                }
            }
        } else {
            const int qrow = q0 + wave * 32 + mt * 16 + l16;
            #pragma unroll
            for (int nt = 0; nt < 4; ++nt) {
                #pragma unroll
                for (int r = 0; r < 4; ++r) {
                    float p = __builtin_amdgcn_exp2f(s[mt][nt][r]);
                    int key = k0 + nt * 16 + quad * 4 + r;
                    if (key > qrow) p = 0.f;
                    lsum += p;
                    pt[mt][nt][r] = (__bf16)p;
                }
            }
        }
        lr[mt] += lsum;
    }
}

// ---------------------------------------------------------------------------
// attn: paired tile compute — h and l q-streams share kf/vf LDS reads.
// ---------------------------------------------------------------------------
static __device__ __forceinline__ void attn_tile_pair(
    const __hip_bfloat16 (*Ksb)[72], const __hip_bfloat16 (*Vtsb)[72],
    int k0, int q0h, int q0l, int wave, int quad, int l16,
    const bf16x8 (&qfh)[2][2], const bf16x8 (&qfl)[2][2],
    f32x4 (&oh)[4][2], f32x4 (&ol)[4][2],
    float (&lh)[2], float (&ll)[2], bool doh, bool dol)
{
    f32x4 sh[2][4], sl[2][4];
    #pragma unroll
    for (int nt = 0; nt < 4; ++nt) {
        bf16x8 kf0 = *reinterpret_cast<const bf16x8*>(&Ksb[nt * 16 + l16][quad * 8]);
        bf16x8 kf1 = *reinterpret_cast<const bf16x8*>(&Ksb[nt * 16 + l16][32 + quad * 8]);
        if (doh) {
            #pragma unroll
            for (int mt = 0; mt < 2; ++mt) {
                f32x4 z = {};
                z = __builtin_amdgcn_mfma_f32_16x16x32_bf16(kf0, qfh[mt][0], z, 0, 0, 0);
                z = __builtin_amdgcn_mfma_f32_16x16x32_bf16(kf1, qfh[mt][1], z, 0, 0, 0);
                sh[mt][nt] = z;
            }
        }
        if (dol) {
            #pragma unroll
            for (int mt = 0; mt < 2; ++mt) {
                f32x4 z = {};
                z = __builtin_amdgcn_mfma_f32_16x16x32_bf16(kf0, qfl[mt][0], z, 0, 0, 0);
                z = __builtin_amdgcn_mfma_f32_16x16x32_bf16(kf1, qfl[mt][1], z, 0, 0, 0);
                sl[mt][nt] = z;
            }
        }
    }
    bf16x4 pth[2][4], ptl[2][4];
    if (doh) exp_phase(sh, pth, lh, k0, q0h, wave, quad, l16);
    if (dol) exp_phase(sl, ptl, ll, k0, q0l, wave, quad, l16);

    #pragma unroll
    for (int cp = 0; cp < 2; ++cp) {
        bf16x8 pfh[2], pfl[2];
        if (doh) {
            #pragma unroll
            for (int mt = 0; mt < 2; ++mt)
                pfh[mt] = concat4(pth[mt][cp * 2], pth[mt][cp * 2 + 1]);
        }
        if (dol) {
            #pragma unroll
            for (int mt = 0; mt < 2; ++mt)
                pfl[mt] = concat4(ptl[mt][cp * 2], ptl[mt][cp * 2 + 1]);
        }
        #pragma unroll
        for (int dt = 0; dt < 4; ++dt) {
            bf16x4 va = *reinterpret_cast<const bf16x4*>(
                &Vtsb[dt * 16 + l16][cp * 32 + quad * 4]);
            bf16x4 vb = *reinterpret_cast<const bf16x4*>(
                &Vtsb[dt * 16 + l16][cp * 32 + 16 + quad * 4]);
            bf16x8 vf = concat4(va, vb);
            if (doh) {
                #pragma unroll
                for (int mt = 0; mt < 2; ++mt)
                    oh[dt][mt] = __builtin_amdgcn_mfma_f32_16x16x32_bf16(
                        vf, pfh[mt], oh[dt][mt], 0, 0, 0);
            }
            if (dol) {
                #pragma unroll
                for (int mt = 0; mt < 2; ++mt)
                    ol[dt][mt] = __builtin_amdgcn_mfma_f32_16x16x32_bf16(
                        vf, pfl[mt], ol[dt][mt], 0, 0, 0);
            }
        }
    }
}

// ---------------------------------------------------------------------------
// Kernel 4: causal flash attention, pair-balanced, dbuf LDS + VGPR prefetch.
// Block xi handles q-tiles {xi, 15-xi} sharing one k-stream. Grid (8, 64).
// ---------------------------------------------------------------------------
__global__ __launch_bounds__(256, 2) void attn_kernel(
    const __hip_bfloat16* __restrict__ Q, const __hip_bfloat16* __restrict__ K,
    const __hip_bfloat16* __restrict__ Vt, __hip_bfloat16* __restrict__ ctx)
{
    const int xi = blockIdx.x;
    const int bh = blockIdx.y;
    const int q0h = (15 - xi) * 128;
    const int q0l = xi * 128;
    const __hip_bfloat16* Qb  = Q  + (size_t)bh * TT * DH;
    const __hip_bfloat16* Kb  = K  + (size_t)bh * TT * DH;
    const __hip_bfloat16* Vtb = Vt + (size_t)bh * DH * TT;

    const int tid = threadIdx.x, wave = tid >> 6, lane = tid & 63;
    const int quad = lane >> 4, l16 = lane & 15;

    __shared__ __hip_bfloat16 Ks[2][64][72];
    __shared__ __hip_bfloat16 Vts[2][64][72];

    bf16x8 qfh[2][2], qfl[2][2];
    #pragma unroll
    for (int mt = 0; mt < 2; ++mt) {
        int rh = q0h + wave * 32 + mt * 16 + l16;
        int rl = q0l + wave * 32 + mt * 16 + l16;
        #pragma unroll
        for (int st = 0; st < 2; ++st) {
            qfh[mt][st] = *reinterpret_cast<const bf16x8*>(
                &Qb[(size_t)rh * DH + st * 32 + quad * 8]);
            qfl[mt][st] = *reinterpret_cast<const bf16x8*>(
                &Qb[(size_t)rl * DH + st * 32 + quad * 8]);
        }
    }

    f32x4 oh[4][2] = {}, ol[4][2] = {};
    float lh[2] = {0.f, 0.f}, ll[2] = {0.f, 0.f};

    const int rr = tid >> 3;          // 0..31
    const int co = (tid & 7) * 8;

    bf16x8 kreg[2], vreg[2];
    #pragma unroll
    for (int i = 0; i < 2; ++i) {
        int r2 = rr + i * 32;
        kreg[i] = *reinterpret_cast<const bf16x8*>(&Kb[(size_t)r2 * DH + co]);
        vreg[i] = *reinterpret_cast<const bf16x8*>(&Vtb[(size_t)r2 * TT + co]);
    }
    #pragma unroll
    for (int i = 0; i < 2; ++i) {
        int r2 = rr + i * 32;
        *reinterpret_cast<bf16x8*>(&Ks[0][r2][co]) = kreg[i];
        *reinterpret_cast<bf16x8*>(&Vts[0][r2][co]) = vreg[i];
    }
    __syncthreads();

    const int nsteps = q0h / 64 + 2;
    for (int step = 0; step < nsteps; ++step) {
        const int k0 = step * 64;
        const int cur = step & 1;
        const bool havenext = (step + 1 < nsteps);
        if (havenext) {
            const int kn = k0 + 64;
            #pragma unroll
            for (int i = 0; i < 2; ++i) {
                int r2 = rr + i * 32;
                kreg[i] = *reinterpret_cast<const bf16x8*>(
                    &Kb[(size_t)(kn + r2) * DH + co]);
                vreg[i] = *reinterpret_cast<const bf16x8*>(
                    &Vtb[(size_t)r2 * TT + kn + co]);
            }
        }
        const bool doh = (k0 <= q0h + wave * 32 + 31);
        const bool dol = (k0 <= q0l + wave * 32 + 31);
        if (doh || dol)
            attn_tile_pair(Ks[cur], Vts[cur], k0, q0h, q0l, wave, quad, l16,
                           qfh, qfl, oh, ol, lh, ll, doh, dol);
        if (havenext) {
            const int nxt = cur ^ 1;
            #pragma unroll
            for (int i = 0; i < 2; ++i) {
                int r2 = rr + i * 32;
                *reinterpret_cast<bf16x8*>(&Ks[nxt][r2][co]) = kreg[i];
                *reinterpret_cast<bf16x8*>(&Vts[nxt][r2][co]) = vreg[i];
            }
        }
        __syncthreads();
    }

    float invh[2], invl[2];
    #pragma unroll
    for (int mt = 0; mt < 2; ++mt) {
        float a = lh[mt];
        a += __shfl_xor(a, 16, 64); a += __shfl_xor(a, 32, 64);
        invh[mt] = 1.0f / a;
        float c = ll[mt];
        c += __shfl_xor(c, 16, 64); c += __shfl_xor(c, 32, 64);
        invl[mt] = 1.0f / c;
    }

    const int b = bh >> 3, hh = bh & 7;
    #pragma unroll
    for (int mt = 0; mt < 2; ++mt) {
        int th = q0h + wave * 32 + mt * 16 + l16;
        int tl2 = q0l + wave * 32 + mt * 16 + l16;
        #pragma unroll
        for (int dt = 0; dt < 4; ++dt) {
            bf16x4 pa, pb;
            #pragma unroll
            for (int r = 0; r < 4; ++r) {
                pa[r] = (__bf16)(oh[dt][mt][r] * invh[mt]);
                pb[r] = (__bf16)(ol[dt][mt][r] * invl[mt]);
            }
            *reinterpret_cast<bf16x4*>(
                &ctx[((size_t)(b * TT + th)) * DD + hh * DH + dt * 16 + quad * 4]) = pa;
            *reinterpret_cast<bf16x4*>(
                &ctx[((size_t)(b * TT + tl2)) * DD + hh * DH + dt * 16 + quad * 4]) = pb;
        }
    }
}

// ---------------------------------------------------------------------------
// Kernel 5: out-proj with global_load_lds staging:
// D[c][t] = sum_d wto[c][d] * ctx[t][d];  out = x + D + bo (coalesced t).
// ---------------------------------------------------------------------------
__global__ __launch_bounds__(256) void oproj_gemm(
    const __hip_bfloat16* __restrict__ WT, const __hip_bfloat16* __restrict__ Actx,
    const float* __restrict__ bo, const float* __restrict__ xres,
    float* __restrict__ outp)
{
    const int m0 = blockIdx.x * 128;   // c tile
    const int n0 = blockIdx.y * 128;   // token tile

    __shared__ __hip_bfloat16 As[128][32];
    __shared__ __hip_bfloat16 Bs[128][32];

    const int tid = threadIdx.x;
    const int wave = tid >> 6, lane = tid & 63;
    const int quad = lane >> 4, l16 = lane & 15;
    const int wy = wave >> 1, wx = wave & 1;

    const int lrow = lane >> 2;
    const int lcol = (lane & 3) * 8;

    f32x4 acc[4][4] = {};

    for (int kt = 0; kt < 512; kt += 32) {
        #pragma unroll
        for (int i = 0; i < 2; ++i) {
            int rbase = wave * 32 + i * 16;
            int row = rbase + lrow;
            async_ld16(&WT[(size_t)(m0 + row) * 512 + kt + lcol], &As[rbase][0]);
            async_ld16(&Actx[(size_t)(n0 + row) * 512 + kt + lcol], &Bs[rbase][0]);
        }
        __syncthreads();
        bf16x8 af[4], bfr[4];
        #pragma unroll
        for (int mt = 0; mt < 4; ++mt)
            af[mt] = *reinterpret_cast<const bf16x8*>(&As[wy * 64 + mt * 16 + l16][quad * 8]);
        #pragma unroll
        for (int nt = 0; nt < 4; ++nt)
            bfr[nt] = *reinterpret_cast<const bf16x8*>(&Bs[wx * 64 + nt * 16 + l16][quad * 8]);
        #pragma unroll
        for (int mt = 0; mt < 4; ++mt)
            #pragma unroll
            for (int nt = 0; nt < 4; ++nt)
                acc[mt][nt] = __builtin_amdgcn_mfma_f32_16x16x32_bf16(
                    af[mt], bfr[nt], acc[mt][nt], 0, 0, 0);
        __syncthreads();
    }

    #pragma unroll
    for (int mt = 0; mt < 4; ++mt) {
        #pragma unroll
        for (int nt = 0; nt < 4; ++nt) {
            int tg = n0 + wx * 64 + nt * 16 + l16;
            int b = tg >> 11, t = tg & 2047;
            #pragma unroll
            for (int r = 0; r < 4; ++r) {
                int c = m0 + wy * 64 + mt * 16 + quad * 4 + r;
                size_t oi = ((size_t)(b * CC + c)) * TT + t;
                outp[oi] = xres[oi] + acc[mt][nt][r] + bo[c];
            }
        }
    }
}

// ---------------------------------------------------------------------------
extern "C" void kernel_launch(void* const* d_in, const int* in_sizes, int n_in,
                              void* d_out, int out_size, void* d_ws, size_t ws_size,
                              hipStream_t stream)
{
    const float* x     = (const float*)d_in[0];
    const float* gamma = (const float*)d_in[1];
    const float* beta  = (const float*)d_in[2];
    const float* wq    = (const float*)d_in[3];
    const float* bq    = (const float*)d_in[4];
    const float* wk    = (const float*)d_in[5];
    const float* bk    = (const float*)d_in[6];
    const float* wv    = (const float*)d_in[7];
    const float* bv    = (const float*)d_in[8];
    const float* wo    = (const float*)d_in[9];
    const float* bo    = (const float*)d_in[10];
    float* out = (float*)d_out;

    char* ws = (char*)d_ws;
    const size_t sz_big = (size_t)BB * TT * DD * sizeof(__hip_bfloat16); // 16 MB
    __hip_bfloat16* hbf = (__hip_bfloat16*)ws; ws += sz_big;
    __hip_bfloat16* qb  = (__hip_bfloat16*)ws; ws += sz_big;
    __hip_bfloat16* kb  = (__hip_bfloat16*)ws; ws += sz_big;
    __hip_bfloat16* vtb = (__hip_bfloat16*)ws; ws += sz_big;
    __hip_bfloat16* ctx = (__hip_bfloat16*)ws; ws += sz_big;
    const size_t sz_w = (size_t)512 * 512 * sizeof(__hip_bfloat16);
    __hip_bfloat16* wtq = (__hip_bfloat16*)ws; ws += sz_w;
    __hip_bfloat16* wtk = (__hip_bfloat16*)ws; ws += sz_w;
    __hip_bfloat16* wtv = (__hip_bfloat16*)ws; ws += sz_w;
    __hip_bfloat16* wto = (__hip_bfloat16*)ws; ws += sz_w;

    prepack_w4<<<dim3(256, 4), 256, 0, stream>>>(wq, wk, wv, wo,
                                                 wtq, wtk, wtv, wto);

    ln_kernel<<<BB * (TT / 32), 256, 0, stream>>>(x, gamma, beta, hbf);

    qkv_gemm<<<dim3(BB * TT / 128, DD / 128, 3), 256, 0, stream>>>(
        hbf, wtq, wtk, wtv, bq, bk, bv, qb, kb, vtb);

    attn_kernel<<<dim3(8, BB * HH), 256, 0, stream>>>(qb, kb, vtb, ctx);

    oproj_gemm<<<dim3(CC / 128, BB * TT / 128), 256, 0, stream>>>(
        wto, ctx, bo, x, out);
}

// Round 6
// 223.972 us; speedup vs baseline: 2.1926x; 1.0740x over previous
//
#include <hip/hip_runtime.h>
#include <hip/hip_bf16.h>

#define BB 8
#define TT 2048
#define CC 512
#define DD 512
#define HH 8
#define DH 64

typedef __bf16 bf16x8 __attribute__((ext_vector_type(8)));
typedef __bf16 bf16x4 __attribute__((ext_vector_type(4)));
typedef float  f32x4  __attribute__((ext_vector_type(4)));

static __device__ __forceinline__ bf16x8 concat4(bf16x4 a, bf16x4 b) {
    bf16x8 r;
    #pragma unroll
    for (int i = 0; i < 4; ++i) { r[i] = a[i]; r[i + 4] = b[i]; }
    return r;
}

// async global->LDS, 16B per lane; lds base must be wave-uniform
static __device__ __forceinline__ void async_ld16(const void* g, void* l) {
    __builtin_amdgcn_global_load_lds(
        (const __attribute__((address_space(1))) void*)g,
        (__attribute__((address_space(3))) void*)l, 16, 0, 0);
}

// ---------------------------------------------------------------------------
// Kernel 1: LayerNorm + transpose (B,C,T) fp32 -> (B*T, C) bf16.
// ---------------------------------------------------------------------------
__global__ __launch_bounds__(256) void ln_kernel(
    const float* __restrict__ x, const float* __restrict__ gamma,
    const float* __restrict__ beta, __hip_bfloat16* __restrict__ h)
{
    const int b  = blockIdx.x >> 6;
    const int t0 = (blockIdx.x & 63) * 32;
    const int tid = threadIdx.x;
    const int tl = tid & 31;
    const int part = tid >> 5;

    const float* xb = x + (size_t)b * CC * TT;

    __shared__ float xs[512][32];    // 64 KB
    float sum = 0.f, sq = 0.f;
    #pragma unroll 8
    for (int ci = 0; ci < 64; ++ci) {
        int c = part * 64 + ci;
        float v = xb[(size_t)c * TT + t0 + tl];
        xs[c][tl] = v;
        sum += v; sq += v * v;
    }
    __shared__ float sA[8][32], sB[8][32];
    sA[part][tl] = sum; sB[part][tl] = sq;
    __syncthreads();
    __shared__ float s_mu[32], s_rstd[32];
    if (part == 0) {
        float s = 0.f, q = 0.f;
        for (int p = 0; p < 8; ++p) { s += sA[p][tl]; q += sB[p][tl]; }
        float mu  = s * (1.0f / 512.0f);
        float var = q * (1.0f / 512.0f) - mu * mu;
        s_mu[tl] = mu;
        s_rstd[tl] = rsqrtf(var + 1e-5f);
    }
    __syncthreads();

    const float mu = s_mu[tl], rstd = s_rstd[tl];
    __shared__ __hip_bfloat16 tileT[32][72];

    for (int chunk = 0; chunk < 8; ++chunk) {
        int cb = chunk * 64 + part * 8;
        #pragma unroll
        for (int j = 0; j < 8; ++j) {
            int c = cb + j;
            float nv = (xs[c][tl] - mu) * rstd * gamma[c] + beta[c];
            tileT[tl][part * 8 + j] = __float2bfloat16(nv);
        }
        __syncthreads();
        int cl = tid & 63, tw = tid >> 6;
        #pragma unroll
        for (int k = 0; k < 8; ++k) {
            int t = tw + k * 4;
            h[((size_t)(b * TT + t0 + t)) * CC + chunk * 64 + cl] = tileT[t][cl];
        }
        __syncthreads();
    }
}

// ---------------------------------------------------------------------------
// Kernel 2: weight prepack (all 4): w (K,N) fp32 -> wt (N,K) bf16
// ---------------------------------------------------------------------------
__global__ __launch_bounds__(256) void prepack_w4(
    const float* __restrict__ w0, const float* __restrict__ w1,
    const float* __restrict__ w2, const float* __restrict__ w3,
    __hip_bfloat16* __restrict__ o0, __hip_bfloat16* __restrict__ o1,
    __hip_bfloat16* __restrict__ o2, __hip_bfloat16* __restrict__ o3)
{
    const float* w; __hip_bfloat16* wt;
    switch (blockIdx.y) {
        case 0: w = w0; wt = o0; break;
        case 1: w = w1; wt = o1; break;
        case 2: w = w2; wt = o2; break;
        default: w = w3; wt = o3; break;
    }
    __shared__ float tile[32][33];
    const int bx = blockIdx.x & 15;
    const int by = blockIdx.x >> 4;
    const int lx = threadIdx.x & 31, ly = threadIdx.x >> 5;
    #pragma unroll
    for (int i = 0; i < 4; ++i) {
        int k = by * 32 + ly + i * 8;
        tile[ly + i * 8][lx] = w[(size_t)k * 512 + bx * 32 + lx];
    }
    __syncthreads();
    #pragma unroll
    for (int i = 0; i < 4; ++i) {
        int n = bx * 32 + ly + i * 8;
        wt[(size_t)n * 512 + by * 32 + lx] = __float2bfloat16(tile[lx][ly + i * 8]);
    }
}

// ---------------------------------------------------------------------------
// Kernel 3: fused QKV GEMM.  global_load_lds staging, BK=64, XOR-swizzled LDS
// (swizzle applied on the GLOBAL column group so the lane-order contract of
// global_load_lds holds; reads XOR with row&7 -> conflict-free b128).
// Q (pre-scaled by log2e/8), K -> (B,H,T,64);  V -> V^T (B,H,64,T) via
// operand-swapped MFMA (accumulates D^T; no LDS transpose in epilogue).
// ---------------------------------------------------------------------------
__global__ __launch_bounds__(256) void qkv_gemm(
    const __hip_bfloat16* __restrict__ A,
    const __hip_bfloat16* __restrict__ wtq, const __hip_bfloat16* __restrict__ wtk,
    const __hip_bfloat16* __restrict__ wtv,
    const float* __restrict__ bq, const float* __restrict__ bk,
    const float* __restrict__ bv,
    __hip_bfloat16* __restrict__ qo, __hip_bfloat16* __restrict__ ko,
    __hip_bfloat16* __restrict__ vt)
{
    const int m0 = blockIdx.x * 128;
    const int n0 = blockIdx.y * 128;
    const __hip_bfloat16* WT; const float* bias; __hip_bfloat16* out;
    if (blockIdx.z == 0)      { WT = wtq; bias = bq; out = qo; }
    else if (blockIdx.z == 1) { WT = wtk; bias = bk; out = ko; }
    else                      { WT = wtv; bias = bv; out = vt; }
    const float sc = (blockIdx.z == 0) ? 0.18033688011112042f : 1.0f;
    const bool vswap = (blockIdx.z == 2);

    __shared__ __hip_bfloat16 As[128][64];
    __shared__ __hip_bfloat16 Bs[128][64];

    const int tid = threadIdx.x;
    const int wave = tid >> 6, lane = tid & 63;
    const int quad = lane >> 4, l16 = lane & 15;
    const int wy = wave >> 1, wx = wave & 1;

    const int r8 = lane >> 3;            // 0..7 row within 8-row issue
    const int c8 = lane & 7;             // col group
    const int cg = (c8 ^ r8) * 8;        // swizzled global col offset (elems)

    f32x4 acc[4][4] = {};

    for (int kt = 0; kt < 512; kt += 64) {
        #pragma unroll
        for (int i = 0; i < 4; ++i) {
            int rbase = wave * 32 + i * 8;
            int row = rbase + r8;
            async_ld16(&A[(size_t)(m0 + row) * 512 + kt + cg], &As[rbase][0]);
            async_ld16(&WT[(size_t)(n0 + row) * 512 + kt + cg], &Bs[rbase][0]);
        }
        __syncthreads();
        #pragma unroll
        for (int kk = 0; kk < 2; ++kk) {
            const int xr = l16 & 7;
            bf16x8 af[4], bfr[4];
            #pragma unroll
            for (int mt = 0; mt < 4; ++mt)
                af[mt] = *reinterpret_cast<const bf16x8*>(
                    &As[wy * 64 + mt * 16 + l16][((kk * 4 + quad) ^ xr) * 8]);
            #pragma unroll
            for (int nt = 0; nt < 4; ++nt)
                bfr[nt] = *reinterpret_cast<const bf16x8*>(
                    &Bs[wx * 64 + nt * 16 + l16][((kk * 4 + quad) ^ xr) * 8]);
            if (!vswap) {
                #pragma unroll
                for (int mt = 0; mt < 4; ++mt)
                    #pragma unroll
                    for (int nt = 0; nt < 4; ++nt)
                        acc[mt][nt] = __builtin_amdgcn_mfma_f32_16x16x32_bf16(
                            af[mt], bfr[nt], acc[mt][nt], 0, 0, 0);
            } else {
                #pragma unroll
                for (int mt = 0; mt < 4; ++mt)
                    #pragma unroll
                    for (int nt = 0; nt < 4; ++nt)
                        acc[mt][nt] = __builtin_amdgcn_mfma_f32_16x16x32_bf16(
                            bfr[nt], af[mt], acc[mt][nt], 0, 0, 0);
            }
        }
        __syncthreads();
    }

    if (!vswap) {
        // C layout: row = token (quad*4+r), col = n (l16)
        #pragma unroll
        for (int nt = 0; nt < 4; ++nt) {
            int n = n0 + wx * 64 + nt * 16 + l16;
            int hh = n >> 6, di = n & 63;
            float bval = bias[n];
            #pragma unroll
            for (int mt = 0; mt < 4; ++mt) {
                #pragma unroll
                for (int r = 0; r < 4; ++r) {
                    int m = m0 + wy * 64 + mt * 16 + quad * 4 + r;
                    int b = m >> 11, t = m & 2047;
                    out[((size_t)((b * HH + hh) * TT + t)) * DH + di] =
                        __float2bfloat16((acc[mt][nt][r] + bval) * sc);
                }
            }
        }
    } else {
        // swapped: C row = d (quad*4+r within nt-tile), col = token (l16)
        #pragma unroll
        for (int nt = 0; nt < 4; ++nt) {
            #pragma unroll
            for (int r = 0; r < 4; ++r) {
                int n = n0 + wx * 64 + nt * 16 + quad * 4 + r;
                int hh = n >> 6, di = n & 63;
                float bval = bias[n];
                #pragma unroll
                for (int mt = 0; mt < 4; ++mt) {
                    int m = m0 + wy * 64 + mt * 16 + l16;
                    int b = m >> 11, t = m & 2047;
                    out[((size_t)((b * HH + hh) * DH + di)) * TT + t] =
                        __float2bfloat16(acc[mt][nt][r] + bval);
                }
            }
        }
    }
}

// ---------------------------------------------------------------------------
// attn tile compute: S^T = K Q^T; P in-register; O^T += Vt P^T   (R4 verbatim)
// ---------------------------------------------------------------------------
static __device__ __forceinline__ void attn_tile(
    const __hip_bfloat16 (*Ksb)[72], const __hip_bfloat16 (*Vtsb)[72],
    int k0, int q0, int wave, int quad, int l16,
    const bf16x8 (&qf)[2][2], f32x4 (&o_acc)[4][2], float (&l_run)[2])
{
    f32x4 s[2][4];
    #pragma unroll
    for (int nt = 0; nt < 4; ++nt) {
        bf16x8 kf0 = *reinterpret_cast<const bf16x8*>(&Ksb[nt * 16 + l16][quad * 8]);
        bf16x8 kf1 = *reinterpret_cast<const bf16x8*>(&Ksb[nt * 16 + l16][32 + quad * 8]);
        #pragma unroll
        for (int mt = 0; mt < 2; ++mt) {
            f32x4 z = {};
            z = __builtin_amdgcn_mfma_f32_16x16x32_bf16(kf0, qf[mt][0], z, 0, 0, 0);
            z = __builtin_amdgcn_mfma_f32_16x16x32_bf16(kf1, qf[mt][1], z, 0, 0, 0);
            s[mt][nt] = z;
        }
    }
    bf16x4 pt[2][4];
    #pragma unroll
    for (int mt = 0; mt < 2; ++mt) {
        const int qrow = q0 + wave * 32 + mt * 16 + l16;
        const bool fullun = (k0 + 63 <= q0 + wave * 32 + mt * 16);
        float lsum = 0.f;
        #pragma unroll
        for (int nt = 0; nt < 4; ++nt) {
            #pragma unroll
            for (int r = 0; r < 4; ++r) {
                float p = __builtin_amdgcn_exp2f(s[mt][nt][r]);
                if (!fullun) {
                    int key = k0 + nt * 16 + quad * 4 + r;
                    if (key > qrow) p = 0.f;
                }
                lsum += p;
                pt[mt][nt][r] = (__bf16)p;
            }
        }
        l_run[mt] += lsum;
    }
    #pragma unroll
    for (int cp = 0; cp < 2; ++cp) {
        bf16x8 pfr[2];
        #pragma unroll
        for (int mt = 0; mt < 2; ++mt)
            pfr[mt] = concat4(pt[mt][cp * 2], pt[mt][cp * 2 + 1]);
        #pragma unroll
        for (int dt = 0; dt < 4; ++dt) {
            bf16x4 va = *reinterpret_cast<const bf16x4*>(
                &Vtsb[dt * 16 + l16][cp * 32 + quad * 4]);
            bf16x4 vb = *reinterpret_cast<const bf16x4*>(
                &Vtsb[dt * 16 + l16][cp * 32 + 16 + quad * 4]);
            bf16x8 vf = concat4(va, vb);
            #pragma unroll
            for (int mt = 0; mt < 2; ++mt)
                o_acc[dt][mt] = __builtin_amdgcn_mfma_f32_16x16x32_bf16(
                    vf, pfr[mt], o_acc[dt][mt], 0, 0, 0);
        }
    }
}

// ---------------------------------------------------------------------------
// Kernel 4: causal flash attention, pair-balanced, dbuf LDS + VGPR prefetch.
// Block xi handles q-tiles {xi, 15-xi} sharing one k-stream. Grid (8, 64).
// (R4 verbatim — measured 69.8 us.)
// ---------------------------------------------------------------------------
__global__ __launch_bounds__(256, 2) void attn_kernel(
    const __hip_bfloat16* __restrict__ Q, const __hip_bfloat16* __restrict__ K,
    const __hip_bfloat16* __restrict__ Vt, __hip_bfloat16* __restrict__ ctx)
{
    const int xi = blockIdx.x;
    const int bh = blockIdx.y;
    const int q0h = (15 - xi) * 128;
    const int q0l = xi * 128;
    const __hip_bfloat16* Qb  = Q  + (size_t)bh * TT * DH;
    const __hip_bfloat16* Kb  = K  + (size_t)bh * TT * DH;
    const __hip_bfloat16* Vtb = Vt + (size_t)bh * DH * TT;

    const int tid = threadIdx.x, wave = tid >> 6, lane = tid & 63;
    const int quad = lane >> 4, l16 = lane & 15;

    __shared__ __hip_bfloat16 Ks[2][64][72];
    __shared__ __hip_bfloat16 Vts[2][64][72];

    bf16x8 qfh[2][2], qfl[2][2];
    #pragma unroll
    for (int mt = 0; mt < 2; ++mt) {
        int rh = q0h + wave * 32 + mt * 16 + l16;
        int rl = q0l + wave * 32 + mt * 16 + l16;
        #pragma unroll
        for (int st = 0; st < 2; ++st) {
            qfh[mt][st] = *reinterpret_cast<const bf16x8*>(
                &Qb[(size_t)rh * DH + st * 32 + quad * 8]);
            qfl[mt][st] = *reinterpret_cast<const bf16x8*>(
                &Qb[(size_t)rl * DH + st * 32 + quad * 8]);
        }
    }

    f32x4 oh[4][2] = {}, ol[4][2] = {};
    float lh[2] = {0.f, 0.f}, ll[2] = {0.f, 0.f};

    const int rr = tid >> 3;          // 0..31
    const int co = (tid & 7) * 8;

    bf16x8 kreg[2], vreg[2];
    #pragma unroll
    for (int i = 0; i < 2; ++i) {
        int r2 = rr + i * 32;
        kreg[i] = *reinterpret_cast<const bf16x8*>(&Kb[(size_t)r2 * DH + co]);
        vreg[i] = *reinterpret_cast<const bf16x8*>(&Vtb[(size_t)r2 * TT + co]);
    }
    #pragma unroll
    for (int i = 0; i < 2; ++i) {
        int r2 = rr + i * 32;
        *reinterpret_cast<bf16x8*>(&Ks[0][r2][co]) = kreg[i];
        *reinterpret_cast<bf16x8*>(&Vts[0][r2][co]) = vreg[i];
    }
    __syncthreads();

    const int nsteps = q0h / 64 + 2;
    for (int step = 0; step < nsteps; ++step) {
        const int k0 = step * 64;
        const int cur = step & 1;
        const bool havenext = (step + 1 < nsteps);
        if (havenext) {
            const int kn = k0 + 64;
            #pragma unroll
            for (int i = 0; i < 2; ++i) {
                int r2 = rr + i * 32;
                kreg[i] = *reinterpret_cast<const bf16x8*>(
                    &Kb[(size_t)(kn + r2) * DH + co]);
                vreg[i] = *reinterpret_cast<const bf16x8*>(
                    &Vtb[(size_t)r2 * TT + kn + co]);
            }
        }
        if (k0 <= q0h + wave * 32 + 31)
            attn_tile(Ks[cur], Vts[cur], k0, q0h, wave, quad, l16, qfh, oh, lh);
        if (k0 <= q0l + wave * 32 + 31)
            attn_tile(Ks[cur], Vts[cur], k0, q0l, wave, quad, l16, qfl, ol, ll);
        if (havenext) {
            const int nxt = cur ^ 1;
            #pragma unroll
            for (int i = 0; i < 2; ++i) {
                int r2 = rr + i * 32;
                *reinterpret_cast<bf16x8*>(&Ks[nxt][r2][co]) = kreg[i];
                *reinterpret_cast<bf16x8*>(&Vts[nxt][r2][co]) = vreg[i];
            }
        }
        __syncthreads();
    }

    float invh[2], invl[2];
    #pragma unroll
    for (int mt = 0; mt < 2; ++mt) {
        float a = lh[mt];
        a += __shfl_xor(a, 16, 64); a += __shfl_xor(a, 32, 64);
        invh[mt] = 1.0f / a;
        float c = ll[mt];
        c += __shfl_xor(c, 16, 64); c += __shfl_xor(c, 32, 64);
        invl[mt] = 1.0f / c;
    }

    const int b = bh >> 3, hh = bh & 7;
    #pragma unroll
    for (int mt = 0; mt < 2; ++mt) {
        int th = q0h + wave * 32 + mt * 16 + l16;
        int tl2 = q0l + wave * 32 + mt * 16 + l16;
        #pragma unroll
        for (int dt = 0; dt < 4; ++dt) {
            bf16x4 pa, pb;
            #pragma unroll
            for (int r = 0; r < 4; ++r) {
                pa[r] = (__bf16)(oh[dt][mt][r] * invh[mt]);
                pb[r] = (__bf16)(ol[dt][mt][r] * invl[mt]);
            }
            *reinterpret_cast<bf16x4*>(
                &ctx[((size_t)(b * TT + th)) * DD + hh * DH + dt * 16 + quad * 4]) = pa;
            *reinterpret_cast<bf16x4*>(
                &ctx[((size_t)(b * TT + tl2)) * DD + hh * DH + dt * 16 + quad * 4]) = pb;
        }
    }
}

// ---------------------------------------------------------------------------
// Kernel 5: out-proj, BK=64 + swizzled global_load_lds staging:
// D[c][t] = sum_d wto[c][d] * ctx[t][d];  out = x + D + bo (coalesced t).
// ---------------------------------------------------------------------------
__global__ __launch_bounds__(256) void oproj_gemm(
    const __hip_bfloat16* __restrict__ WT, const __hip_bfloat16* __restrict__ Actx,
    const float* __restrict__ bo, const float* __restrict__ xres,
    float* __restrict__ outp)
{
    const int m0 = blockIdx.x * 128;   // c tile
    const int n0 = blockIdx.y * 128;   // token tile

    __shared__ __hip_bfloat16 As[128][64];
    __shared__ __hip_bfloat16 Bs[128][64];

    const int tid = threadIdx.x;
    const int wave = tid >> 6, lane = tid & 63;
    const int quad = lane >> 4, l16 = lane & 15;
    const int wy = wave >> 1, wx = wave & 1;

    const int r8 = lane >> 3;
    const int c8 = lane & 7;
    const int cg = (c8 ^ r8) * 8;

    f32x4 acc[4][4] = {};

    for (int kt = 0; kt < 512; kt += 64) {
        #pragma unroll
        for (int i = 0; i < 4; ++i) {
            int rbase = wave * 32 + i * 8;
            int row = rbase + r8;
            async_ld16(&WT[(size_t)(m0 + row) * 512 + kt + cg], &As[rbase][0]);
            async_ld16(&Actx[(size_t)(n0 + row) * 512 + kt + cg], &Bs[rbase][0]);
        }
        __syncthreads();
        #pragma unroll
        for (int kk = 0; kk < 2; ++kk) {
            const int xr = l16 & 7;
            bf16x8 af[4], bfr[4];
            #pragma unroll
            for (int mt = 0; mt < 4; ++mt)
                af[mt] = *reinterpret_cast<const bf16x8*>(
                    &As[wy * 64 + mt * 16 + l16][((kk * 4 + quad) ^ xr) * 8]);
            #pragma unroll
            for (int nt = 0; nt < 4; ++nt)
                bfr[nt] = *reinterpret_cast<const bf16x8*>(
                    &Bs[wx * 64 + nt * 16 + l16][((kk * 4 + quad) ^ xr) * 8]);
            #pragma unroll
            for (int mt = 0; mt < 4; ++mt)
                #pragma unroll
                for (int nt = 0; nt < 4; ++nt)
                    acc[mt][nt] = __builtin_amdgcn_mfma_f32_16x16x32_bf16(
                        af[mt], bfr[nt], acc[mt][nt], 0, 0, 0);
        }
        __syncthreads();
    }

    #pragma unroll
    for (int mt = 0; mt < 4; ++mt) {
        #pragma unroll
        for (int nt = 0; nt < 4; ++nt) {
            int tg = n0 + wx * 64 + nt * 16 + l16;
            int b = tg >> 11, t = tg & 2047;
            #pragma unroll
            for (int r = 0; r < 4; ++r) {
                int c = m0 + wy * 64 + mt * 16 + quad * 4 + r;
                size_t oi = ((size_t)(b * CC + c)) * TT + t;
                outp[oi] = xres[oi] + acc[mt][nt][r] + bo[c];
            }
        }
    }
}

// ---------------------------------------------------------------------------
extern "C" void kernel_launch(void* const* d_in, const int* in_sizes, int n_in,
                              void* d_out, int out_size, void* d_ws, size_t ws_size,
                              hipStream_t stream)
{
    const float* x     = (const float*)d_in[0];
    const float* gamma = (const float*)d_in[1];
    const float* beta  = (const float*)d_in[2];
    const float* wq    = (const float*)d_in[3];
    const float* bq    = (const float*)d_in[4];
    const float* wk    = (const float*)d_in[5];
    const float* bk    = (const float*)d_in[6];
    const float* wv    = (const float*)d_in[7];
    const float* bv    = (const float*)d_in[8];
    const float* wo    = (const float*)d_in[9];
    const float* bo    = (const float*)d_in[10];
    float* out = (float*)d_out;

    char* ws = (char*)d_ws;
    const size_t sz_big = (size_t)BB * TT * DD * sizeof(__hip_bfloat16); // 16 MB
    __hip_bfloat16* hbf = (__hip_bfloat16*)ws; ws += sz_big;
    __hip_bfloat16* qb  = (__hip_bfloat16*)ws; ws += sz_big;
    __hip_bfloat16* kb  = (__hip_bfloat16*)ws; ws += sz_big;
    __hip_bfloat16* vtb = (__hip_bfloat16*)ws; ws += sz_big;
    __hip_bfloat16* ctx = (__hip_bfloat16*)ws; ws += sz_big;
    const size_t sz_w = (size_t)512 * 512 * sizeof(__hip_bfloat16);
    __hip_bfloat16* wtq = (__hip_bfloat16*)ws; ws += sz_w;
    __hip_bfloat16* wtk = (__hip_bfloat16*)ws; ws += sz_w;
    __hip_bfloat16* wtv = (__hip_bfloat16*)ws; ws += sz_w;
    __hip_bfloat16* wto = (__hip_bfloat16*)ws; ws += sz_w;

    prepack_w4<<<dim3(256, 4), 256, 0, stream>>>(wq, wk, wv, wo,
                                                 wtq, wtk, wtv, wto);

    ln_kernel<<<BB * (TT / 32), 256, 0, stream>>>(x, gamma, beta, hbf);

    qkv_gemm<<<dim3(BB * TT / 128, DD / 128, 3), 256, 0, stream>>>(
        hbf, wtq, wtk, wtv, bq, bk, bv, qb, kb, vtb);

    attn_kernel<<<dim3(8, BB * HH), 256, 0, stream>>>(qb, kb, vtb, ctx);

    oproj_gemm<<<dim3(CC / 128, BB * TT / 128), 256, 0, stream>>>(
        wto, ctx, bo, x, out);
}